// Round 10
// baseline (362.769 us; speedup 1.0000x reference)
//
#include <hip/hip_runtime.h>
#include <cstdint>
#include <cstddef>

#define HIDDEN 2048
#define HEADS 16
#define HD 128
#define BSZ 2
#define SEQ 2048
#define MTOT (BSZ * SEQ)        // 4096
#define NQKV (HIDDEN + 2 * HD)  // 2304
#define SL2E 0.12751743f        // (1/sqrt(128)) * log2(e)

typedef unsigned short ushort_t;
typedef __attribute__((ext_vector_type(8))) __bf16 bf16x8;
typedef __attribute__((ext_vector_type(4))) float f32x4;
typedef __attribute__((ext_vector_type(16))) float f32x16;

typedef __attribute__((address_space(3))) unsigned int as3_u32;
typedef __attribute__((address_space(1))) const unsigned int as1_u32;

// fp32 -> bf16 round-to-nearest-even
__device__ __forceinline__ ushort_t f2bf(float x) {
  union { float f; unsigned u; } v; v.f = x;
  unsigned r = v.u + 0x7fffu + ((v.u >> 16) & 1u);
  return (ushort_t)(r >> 16);
}
// pack two fp32 -> bf16x2 (truncation; bias cancels in normalized softmax)
__device__ __forceinline__ unsigned pk_bf16(float a, float b) {
  union { float f; unsigned u; } x, y; x.f = a; y.f = b;
  return (x.u >> 16) | (y.u & 0xFFFF0000u);
}

// async global->LDS, 16B per lane; lds dst is wave-uniform (HW adds lane*16)
__device__ __forceinline__ void gld16(const void* g, void* lds) {
  __builtin_amdgcn_global_load_lds((as1_u32*)g, (as3_u32*)lds, 16, 0, 0);
}

// barrier with compiler memory fence (raw s_barrier does NOT fence the
// compiler; gld16/ds ops must not drift across phase boundaries)
__device__ __forceinline__ void barf() {
  asm volatile("" ::: "memory");
  __builtin_amdgcn_s_barrier();
  asm volatile("" ::: "memory");
}

// ---------------------------------------------------------------------------
// Fused preprocessing (proven in round 9; biasQKV gets 16 KB — NQKV floats
// = 9216 B; the old 4096 B allocation was the rounds-6-8 corruption bug).
// Block ranges (all 256-thread, branch is block-uniform):
//   [0, NM)              mask_flags   per (b,q128,k64) 0/1/2
//   [NM, +N0)            cvt_bf16     X f32 -> Xb bf16 (float4/ushort4)
//   [.., +N1)            cvtT_qkv     Wq|Wk|Wv -> WT (2304x2048), Wq * SL2E
//   [.., +N2)            cvtT         Wo -> WoT (2048x2048)
//   [.., +N4)            concat_bias  biasQKV (Q-part * SL2E)
// ---------------------------------------------------------------------------
#define PREP_NM (32 * 16 * BSZ)                  // 1024
#define PREP_N0 (MTOT * HIDDEN / 4 / 256)        // 8192
#define PREP_N1 ((NQKV / 32) * (HIDDEN / 32))    // 4608
#define PREP_N2 ((HIDDEN / 32) * (HIDDEN / 32))  // 4096
#define PREP_N4 ((NQKV + 255) / 256)             // 9
#define PREP_NB (PREP_NM + PREP_N0 + PREP_N1 + PREP_N2 + PREP_N4)

__global__ __launch_bounds__(256) void prep_kernel(
    const float* __restrict__ X, ushort_t* __restrict__ Xb,
    const float* __restrict__ Wq, const float* __restrict__ Wk,
    const float* __restrict__ Wv, ushort_t* __restrict__ WT,
    const float* __restrict__ Wo, ushort_t* __restrict__ WoT,
    const int* __restrict__ mask, int* __restrict__ flags,
    const float* __restrict__ bq, const float* __restrict__ bk,
    const float* __restrict__ bv, float* __restrict__ biasQKV) {
  __shared__ float tileF[32][36];
  __shared__ int sAO[8];
  const int t = threadIdx.x;
  int j = blockIdx.x;

  if (j < PREP_NM) {  // ---- mask_flags (long-pole blocks first) ----
    const int kt = j & 31, qt = (j >> 5) & 15, b = j >> 9;
    int allv = 1, anyv = 0;
    const size_t base = (size_t)b * SEQ * SEQ + (size_t)qt * 128 * SEQ + kt * 64;
    for (int i = t; i < 2048; i += 256) {  // 128 rows x 16 int4
      const int row = i >> 4, c4 = (i & 15) << 2;
      const int4 v = *(const int4*)(mask + base + (size_t)row * SEQ + c4);
      const int nz = (v.x != 0) & (v.y != 0) & (v.z != 0) & (v.w != 0);
      const int nzany = (v.x != 0) | (v.y != 0) | (v.z != 0) | (v.w != 0);
      allv &= nz; anyv |= nzany;
    }
    const int wAll = __all(allv), wAny = __any(anyv);
    if ((t & 63) == 0) { sAO[t >> 6] = wAll; sAO[4 + (t >> 6)] = wAny; }
    __syncthreads();
    if (t == 0) {
      const int A = sAO[0] & sAO[1] & sAO[2] & sAO[3];
      const int O = sAO[4] | sAO[5] | sAO[6] | sAO[7];
      flags[(b * 16 + qt) * 32 + kt] = A ? 2 : (O ? 1 : 0);
    }
    return;
  }
  j -= PREP_NM;

  if (j < PREP_N0) {  // ---- cvt_bf16 (exact coverage, no bounds check) ----
    const int i = j * 256 + t;
    float4 v = ((const float4*)X)[i];
    ushort4 o;
    o.x = f2bf(v.x); o.y = f2bf(v.y); o.z = f2bf(v.z); o.w = f2bf(v.w);
    ((ushort4*)Xb)[i] = o;
    return;
  }
  j -= PREP_N0;

  if (j < PREP_N1) {  // ---- cvtT_qkv ----
    const int nb = (j % (NQKV / 32)) * 32, kb = (j / (NQKV / 32)) * 32;
    const float* W; int N, nc; float scale;
    if (nb < HIDDEN)           { W = Wq; N = HIDDEN; nc = nb;               scale = SL2E; }
    else if (nb < HIDDEN + HD) { W = Wk; N = HD;     nc = nb - HIDDEN;      scale = 1.f; }
    else                       { W = Wv; N = HD;     nc = nb - HIDDEN - HD; scale = 1.f; }
    {
      int row = t >> 3, c4 = (t & 7) << 2;
      float4 v = *(const float4*)(W + (size_t)(kb + row) * N + nc + c4);
      tileF[row][c4] = v.x * scale; tileF[row][c4 + 1] = v.y * scale;
      tileF[row][c4 + 2] = v.z * scale; tileF[row][c4 + 3] = v.w * scale;
    }
    __syncthreads();
    {
      int nl = t >> 3, k4 = (t & 7) << 2;
      ushort4 o;
      o.x = f2bf(tileF[k4 + 0][nl]); o.y = f2bf(tileF[k4 + 1][nl]);
      o.z = f2bf(tileF[k4 + 2][nl]); o.w = f2bf(tileF[k4 + 3][nl]);
      *(ushort4*)(WT + (size_t)(nb + nl) * HIDDEN + kb + k4) = o;
    }
    return;
  }
  j -= PREP_N1;

  if (j < PREP_N2) {  // ---- cvtT (Wo -> WoT), K=N=HIDDEN ----
    const int nb = (j % (HIDDEN / 32)) * 32, kb = (j / (HIDDEN / 32)) * 32;
    {
      int row = t >> 3, c4 = (t & 7) << 2;
      float4 v = *(const float4*)(Wo + (size_t)(kb + row) * HIDDEN + nb + c4);
      tileF[row][c4] = v.x; tileF[row][c4 + 1] = v.y;
      tileF[row][c4 + 2] = v.z; tileF[row][c4 + 3] = v.w;
    }
    __syncthreads();
    {
      int nl = t >> 3, k4 = (t & 7) << 2;
      ushort4 o;
      o.x = f2bf(tileF[k4 + 0][nl]); o.y = f2bf(tileF[k4 + 1][nl]);
      o.z = f2bf(tileF[k4 + 2][nl]); o.w = f2bf(tileF[k4 + 3][nl]);
      *(ushort4*)(WoT + (size_t)(nb + nl) * HIDDEN + kb + k4) = o;
    }
    return;
  }
  j -= PREP_N2;

  {  // ---- concat_bias ----
    const int i = j * 256 + t;
    if (i < NQKV)
      biasQKV[i] = (i < HIDDEN) ? bq[i] * SL2E
                 : (i < HIDDEN + HD ? bk[i - HIDDEN] : bv[i - HIDDEN - HD]);
  }
}

// ---------------------------------------------------------------------------
// bf16 MFMA GEMM, round-16: 256x256 / BK=64 / 512 threads (8 waves 2Mx4N),
// 8-phase, DEEP counted vmcnt. v3 of this template; v1/v2 (r4/r5) ran at 52%
// of m201's per-block rate because their vmcnt waited on loads issued only
// 2-3 phases (~500 cyc) earlier — less than L2/HBM latency. v3 stages each
// K-tile in ONE burst (8 gld16/wave) at P4/P8, immediately after the barrier
// that frees the slot (A-region consumed at P3 read into regs), and waits
// vmcnt(8): the 8 confirmed loads were issued 4 phases (~800+ cyc) earlier
// at the PREVIOUS P8/P4 — full latency hidden, never drains to 0 (T4).
//   P1: rd A-lo,B-lo(s); MFMA q(0,0)      P5: same on s^1
//   P2: rd B-hi(s);      MFMA q(0,1)      P6: ...
//   P3: rd A-hi(s);      MFMA q(1,1)      P7: ...
//   P4: stageAll(s,t+2); vmcnt(8); MFMA q(1,0)   P8: stageAll(s^1,t+3); vmcnt(8)
// Race-check: P4 has no LDS reads (MFMA from regs: A-hi @P3, B-lo @P1);
// all waves' reads of slot s completed at the P3-end barrier before any
// wave's P4 stage can land. Registers: acc 128 + af 32 + b0/b1 32 ≈ 220
// VGPR < 256, so 8 waves co-resident. FUSEV: QKV-GEMM epilogue also
// scatter-writes the V-slice transposed (Vt), replacing transpose_v_kernel.
// ---------------------------------------------------------------------------
template <int OUTF32, int FUSEV>
__global__ __launch_bounds__(512, 1) void gemm_mfma8(
    const ushort_t* __restrict__ A, const ushort_t* __restrict__ Bt,
    const float* __restrict__ bias, void* __restrict__ C,
    ushort_t* __restrict__ Vt, int M, int N, int K, int nm_per_xcd) {
  __shared__ ushort_t As[2][256 * 64];  // 64 KB
  __shared__ ushort_t Bs[2][256 * 64];  // 64 KB
  const int t = threadIdx.x;
  const int w = t >> 6, l = t & 63;
  const int id = blockIdx.x;
  const int xcd = id & 7, jb = id >> 3;
  const int mt = xcd * nm_per_xcd + (jb % nm_per_xcd);
  const int nt = jb / nm_per_xcd;
  const int mb = mt * 256, nb = nt * 256;
  const int wm = (w >> 2) * 128, wn = (w & 3) * 64;
  const int fl = l & 15, g = l >> 4;
  const int srow = l >> 3;
  const int clog = (l & 7) ^ (srow & 7);
  const int ntile = K >> 6;

  // stage ALL 4 half-tiles (A h0,h1 + B h0,h1) of K-tile kt into slot s:
  // 8 gld16/wave; 8 waves cover the full 256x64 A and B tiles.
  auto stageAll = [&](int s, int kt) {
#pragma unroll
    for (int half = 0; half < 2; ++half) {
      const int rr = half * 128 + w * 16;
#pragma unroll
      for (int jj = 0; jj < 2; ++jj) {
        gld16(A + (size_t)(mb + rr + jj * 8 + srow) * K + kt * 64 + clog * 8,
              &As[s][(rr + jj * 8) * 64]);
        gld16(Bt + (size_t)(nb + rr + jj * 8 + srow) * K + kt * 64 + clog * 8,
              &Bs[s][(rr + jj * 8) * 64]);
      }
    }
  };

  f32x4 acc[8][4];
#pragma unroll
  for (int i = 0; i < 8; ++i)
#pragma unroll
    for (int jf = 0; jf < 4; ++jf) acc[i][jf] = (f32x4){0.f, 0.f, 0.f, 0.f};

  // prologue: tiles 0 -> slot0, 1 -> slot1; confirm slot0 (8 newer allowed)
  stageAll(0, 0);
  stageAll(1, 1);
  asm volatile("s_waitcnt vmcnt(8)" ::: "memory");
  barf();

  for (int it = 0; it < ntile / 2; ++it) {
    int kc = 2 * it + 2; if (kc >= ntile) kc = ntile - 1;  // dead-clamped tail
    int kd = 2 * it + 3; if (kd >= ntile) kd = ntile - 1;

    bf16x8 af[4][2], b0[2][2], b1[2][2];

#pragma unroll
    for (int h = 0; h < 2; ++h) {
      const ushort_t* Ac = As[h];
      const ushort_t* Bc = Bs[h];

      // ---- phase 1: read A-lo + B-lo; MFMA quad(0,0) ----
#pragma unroll
      for (int i = 0; i < 4; ++i) {
        const int m = wm + i * 16 + fl;
#pragma unroll
        for (int s2 = 0; s2 < 2; ++s2)
          af[i][s2] =
              *(const bf16x8*)&Ac[m * 64 + (((s2 << 2) + g) ^ (fl & 7)) * 8];
      }
#pragma unroll
      for (int jf = 0; jf < 2; ++jf) {
        const int n = wn + jf * 16 + fl;
#pragma unroll
        for (int s2 = 0; s2 < 2; ++s2)
          b0[jf][s2] =
              *(const bf16x8*)&Bc[n * 64 + (((s2 << 2) + g) ^ (fl & 7)) * 8];
      }
      barf();
      asm volatile("s_waitcnt lgkmcnt(0)" ::: "memory");
      __builtin_amdgcn_sched_barrier(0);
      __builtin_amdgcn_s_setprio(1);
#pragma unroll
      for (int i = 0; i < 4; ++i)
#pragma unroll
        for (int jf = 0; jf < 2; ++jf)
#pragma unroll
          for (int s2 = 0; s2 < 2; ++s2)
            acc[i][jf] = __builtin_amdgcn_mfma_f32_16x16x32_bf16(
                af[i][s2], b0[jf][s2], acc[i][jf], 0, 0, 0);
      __builtin_amdgcn_s_setprio(0);
      barf();

      // ---- phase 2: read B-hi; MFMA quad(0,1) ----
#pragma unroll
      for (int jf = 0; jf < 2; ++jf) {
        const int n = wn + (2 + jf) * 16 + fl;
#pragma unroll
        for (int s2 = 0; s2 < 2; ++s2)
          b1[jf][s2] =
              *(const bf16x8*)&Bc[n * 64 + (((s2 << 2) + g) ^ (fl & 7)) * 8];
      }
      barf();
      asm volatile("s_waitcnt lgkmcnt(0)" ::: "memory");
      __builtin_amdgcn_sched_barrier(0);
      __builtin_amdgcn_s_setprio(1);
#pragma unroll
      for (int i = 0; i < 4; ++i)
#pragma unroll
        for (int jf = 0; jf < 2; ++jf)
#pragma unroll
          for (int s2 = 0; s2 < 2; ++s2)
            acc[i][2 + jf] = __builtin_amdgcn_mfma_f32_16x16x32_bf16(
                af[i][s2], b1[jf][s2], acc[i][2 + jf], 0, 0, 0);
      __builtin_amdgcn_s_setprio(0);
      barf();

      // ---- phase 3: read A-hi; MFMA quad(1,1) ----
#pragma unroll
      for (int i = 0; i < 4; ++i) {
        const int m = wm + (4 + i) * 16 + fl;
#pragma unroll
        for (int s2 = 0; s2 < 2; ++s2)
          af[i][s2] =
              *(const bf16x8*)&Ac[m * 64 + (((s2 << 2) + g) ^ (fl & 7)) * 8];
      }
      barf();
      asm volatile("s_waitcnt lgkmcnt(0)" ::: "memory");
      __builtin_amdgcn_sched_barrier(0);
      __builtin_amdgcn_s_setprio(1);
#pragma unroll
      for (int i = 0; i < 4; ++i)
#pragma unroll
        for (int jf = 0; jf < 2; ++jf)
#pragma unroll
          for (int s2 = 0; s2 < 2; ++s2)
            acc[4 + i][2 + jf] = __builtin_amdgcn_mfma_f32_16x16x32_bf16(
                af[i][s2], b1[jf][s2], acc[4 + i][2 + jf], 0, 0, 0);
      __builtin_amdgcn_s_setprio(0);
      barf();

      // ---- phase 4: stage next tile for this slot (burst); deep vmcnt;
      //      MFMA quad(1,0) from registers (no LDS reads this phase) ----
      stageAll(h, h == 0 ? kc : kd);
      asm volatile("s_waitcnt vmcnt(8)" ::: "memory");
      barf();
      __builtin_amdgcn_s_setprio(1);
#pragma unroll
      for (int i = 0; i < 4; ++i)
#pragma unroll
        for (int jf = 0; jf < 2; ++jf)
#pragma unroll
          for (int s2 = 0; s2 < 2; ++s2)
            acc[4 + i][jf] = __builtin_amdgcn_mfma_f32_16x16x32_bf16(
                af[i][s2], b0[jf][s2], acc[4 + i][jf], 0, 0, 0);
      __builtin_amdgcn_s_setprio(0);
      barf();
    }
  }

  // epilogue (+ fused V-transpose write for the QKV GEMM: V cols >= 2176)
#pragma unroll
  for (int jf = 0; jf < 4; ++jf) {
    const int col = nb + wn + jf * 16 + fl;
    const float bv = bias[col];
    const int dv = col - (HIDDEN + HD);
#pragma unroll
    for (int i = 0; i < 8; ++i) {
      const int row0 = mb + wm + i * 16 + g * 4;
#pragma unroll
      for (int r = 0; r < 4; ++r) {
        const float val = acc[i][jf][r] + bv;
        if (OUTF32) {
          ((float*)C)[(size_t)(row0 + r) * N + col] = val;
        } else {
          const ushort_t bb = f2bf(val);
          ((ushort_t*)C)[(size_t)(row0 + r) * N + col] = bb;
          if (FUSEV && dv >= 0)
            Vt[(size_t)dv * MTOT + row0 + r] = bb;
        }
      }
    }
  }
}

// ---------------------------------------------------------------------------
// MFMA flash attention (unchanged: 82 us, 0 bank conflicts, 2 blocks/CU).
// ---------------------------------------------------------------------------
__global__ __launch_bounds__(256, 2) void flash_mfma(
    const ushort_t* __restrict__ QKV,  // (4096, 2304) bf16; Q pre-scaled
    const ushort_t* __restrict__ Vt,   // (128, 4096) bf16
    const int* __restrict__ mask,      // (B, S, S)
    const int* __restrict__ flags,     // (B, 16, 32)
    ushort_t* __restrict__ Ab)         // (4096, 2048) bf16
{
  __shared__ ushort_t Kbuf[2][64 * 128];  // 32 KB: key rows x 128 k-dim
  __shared__ ushort_t Vbuf[2][64 * 128];  // 32 KB: paired-d rows x (2x8) chunks

  const int qt = blockIdx.x, h = blockIdx.y, b = blockIdx.z;
  const int t = threadIdx.x, w = t >> 6, l = t & 63;
  const int q31 = l & 31, hi = l >> 5;
  const int qbase = qt * 128;
  const int qrow = qbase + w * 32 + q31;  // within-batch q row (B-col index)

  // Q as B-fragments: col=q31, k = ks*16 + hi*8 + j (exp2 domain, pre-scaled)
  bf16x8 qf[8];
#pragma unroll
  for (int ks = 0; ks < 8; ++ks)
    qf[ks] = *(const bf16x8*)(QKV + (size_t)(b * SEQ + qrow) * NQKV + h * HD +
                              ks * 16 + hi * 8);

  // ones B-frag for l: B[col=q31][k] = (q31==0) ? 1.0 : 0
  bf16x8 onesf;
  {
    const ushort_t ov = (q31 == 0) ? (ushort_t)0x3F80 : (ushort_t)0;
#pragma unroll
    for (int jj = 0; jj < 8; ++jj) ((ushort_t*)&onesf)[jj] = ov;
  }

  // prologue: prefetch K(0),V(0) -> buffer 0
#pragma unroll
  for (int j = 0; j < 4; ++j) {
    const int inst = w * 4 + j;
    // K: 256B rows; phys chunk (l&15) holds logical (l&15)^(krow&15)
    const int krow = inst * 4 + (l >> 4);
    const int ck = (l & 15) ^ (krow & 15);
    gld16(QKV + (size_t)(b * SEQ + krow) * NQKV + HIDDEN + ck * 8,
          &Kbuf[0][inst * 512]);
    // V: LDS row r holds d=2r,2r+1; phys p = clog ^ (r&15), clog=(d&1)*8+kc
    const int vr = inst * 4 + (l >> 4);
    const int clog = (l & 15) ^ (vr & 15);
    const int d = 2 * vr + (clog >> 3);
    gld16(Vt + (size_t)d * MTOT + b * SEQ + (clog & 7) * 8,
          &Vbuf[0][inst * 512]);
  }

  const size_t mbase = (size_t)b * SEQ * SEQ;

  f32x16 oacc[4], lacc;
#pragma unroll
  for (int d = 0; d < 4; ++d)
#pragma unroll
    for (int r = 0; r < 16; ++r) oacc[d][r] = 0.f;
#pragma unroll
  for (int r = 0; r < 16; ++r) lacc[r] = 0.f;

  int cur = 0;
  for (int kt = 0; kt < SEQ / 64; ++kt) {
    const int kbase = kt * 64;
    const int flag = flags[((b * 16 + qt) << 5) + kt];  // block-uniform
    __syncthreads();  // buf[cur] DMAs drained; prev tile done with buf[cur^1]

    // prefetch K(kt+1), V(kt+1) -> buf[cur^1] (clamped on last tile)
    {
      const int knb = (kt + 1 < SEQ / 64) ? (kbase + 64) : kbase;
#pragma unroll
      for (int j = 0; j < 4; ++j) {
        const int inst = w * 4 + j;
        const int krow = inst * 4 + (l >> 4);
        const int ck = (l & 15) ^ (krow & 15);
        gld16(QKV + (size_t)(b * SEQ + knb + krow) * NQKV + HIDDEN + ck * 8,
              &Kbuf[cur ^ 1][inst * 512]);
        const int vr = inst * 4 + (l >> 4);
        const int clog = (l & 15) ^ (vr & 15);
        const int d = 2 * vr + (clog >> 3);
        gld16(Vt + (size_t)d * MTOT + b * SEQ + knb + (clog & 7) * 8,
              &Vbuf[cur ^ 1][inst * 512]);
      }
    }

    // ---- S^T = K·Q^T from Kbuf[cur]: A = K rows (key), B = Q cols (q) ----
    const ushort_t* Kc = &Kbuf[cur][0];
    f32x16 sc[2];
#pragma unroll
    for (int kk = 0; kk < 2; ++kk)
#pragma unroll
      for (int r = 0; r < 16; ++r) sc[kk][r] = 0.f;

    __builtin_amdgcn_s_setprio(1);
#pragma unroll
    for (int ks = 0; ks < 8; ++ks)
#pragma unroll
      for (int kk = 0; kk < 2; ++kk) {
        const int key = kk * 32 + q31;  // A-row = lane&31
        const bf16x8 kf = *(const bf16x8*)&Kc[key * 128 +
                                              (((ks << 1) + hi) ^ (key & 15)) * 8];
        sc[kk] = __builtin_amdgcn_mfma_f32_32x32x16_bf16(kf, qf[ks], sc[kk],
                                                         0, 0, 0);
      }
    __builtin_amdgcn_s_setprio(0);

    if (flag != 2) {  // mixed/empty tile: per-element mask fallback
#pragma unroll
      for (int kk = 0; kk < 2; ++kk)
#pragma unroll
        for (int r = 0; r < 16; ++r) {
          const int key = kbase + kk * 32 + (r & 3) + ((r >> 2) << 3) + (hi << 2);
          if (!mask[mbase + (size_t)qrow * SEQ + key]) sc[kk][r] = -1e30f;
        }
    }

    // ---- P = exp2(S^T); pack bf16; permlane32_swap -> PA A-frags in regs ----
    bf16x8 pa[4];
#pragma unroll
    for (int kk = 0; kk < 2; ++kk) {
      float pv[16];
#pragma unroll
      for (int r = 0; r < 16; ++r) pv[r] = __builtin_amdgcn_exp2f(sc[kk][r]);
#pragma unroll
      for (int half = 0; half < 2; ++half) {
        const int bs = half * 8;
        unsigned a0 = pk_bf16(pv[bs + 0], pv[bs + 1]);
        unsigned a1 = pk_bf16(pv[bs + 2], pv[bs + 3]);
        unsigned b0 = pk_bf16(pv[bs + 4], pv[bs + 5]);
        unsigned b1 = pk_bf16(pv[bs + 6], pv[bs + 7]);
        asm("v_permlane32_swap_b32 %0, %1" : "+v"(a0), "+v"(b0));
        asm("v_permlane32_swap_b32 %0, %1" : "+v"(a1), "+v"(b1));
        union { unsigned u[4]; bf16x8 v; } uu;
        uu.u[0] = a0; uu.u[1] = a1; uu.u[2] = b0; uu.u[3] = b1;
        pa[kk * 2 + half] = uu.v;
      }
    }

    // ---- O += P·V (B-frags from Vbuf[cur], paired-row layout); l += P·ones --
    const ushort_t* Vc = &Vbuf[cur][0];
    __builtin_amdgcn_s_setprio(1);
#pragma unroll
    for (int ks = 0; ks < 4; ++ks) {
#pragma unroll
      for (int dt = 0; dt < 4; ++dt) {
        const int d = dt * 32 + q31;  // B-col = lane&31
        const int vr = d >> 1;
        const int clog = ((d & 1) << 3) + (ks << 1) + hi;
        const bf16x8 vf =
            *(const bf16x8*)&Vc[vr * 128 + (clog ^ (vr & 15)) * 8];
        oacc[dt] = __builtin_amdgcn_mfma_f32_32x32x16_bf16(pa[ks], vf,
                                                           oacc[dt], 0, 0, 0);
      }
      lacc = __builtin_amdgcn_mfma_f32_32x32x16_bf16(pa[ks], onesf, lacc,
                                                     0, 0, 0);
    }
    __builtin_amdgcn_s_setprio(0);
    cur ^= 1;
  }

  // ---- epilogue: l lives in col 0 (lanes 0 and 32); D row = q = crow ----
#pragma unroll
  for (int r = 0; r < 16; ++r) {
    const float ls = __shfl(lacc[r], l & 32, 64);
    const float invl = 1.0f / ls;
    const int row = b * SEQ + qbase + w * 32 + (r & 3) + ((r >> 2) << 3) +
                    (hi << 2);
#pragma unroll
    for (int dt = 0; dt < 4; ++dt)
      Ab[(size_t)row * HIDDEN + h * HD + dt * 32 + q31] =
          f2bf(oacc[dt][r] * invl);
  }
}

// ---------------------------------------------------------------------------
extern "C" void kernel_launch(void* const* d_in, const int* in_sizes, int n_in,
                              void* d_out, int out_size, void* d_ws, size_t ws_size,
                              hipStream_t stream) {
  const float* X  = (const float*)d_in[0];
  const int* mask = (const int*)d_in[1];
  const float* Wq = (const float*)d_in[2];
  const float* bq = (const float*)d_in[3];
  const float* Wk = (const float*)d_in[4];
  const float* bk = (const float*)d_in[5];
  const float* Wv = (const float*)d_in[6];
  const float* bv = (const float*)d_in[7];
  const float* Wo = (const float*)d_in[8];
  const float* bo = (const float*)d_in[9];
  float* out = (float*)d_out;

  char* p = (char*)d_ws;
  int* flags     = (int*)p;      p += BSZ * 16 * 32 * 4;   // 4 KB
  float* biasQKV = (float*)p;    p += 16384;  // NQKV floats = 9216 B; 16 KB reserved
  ushort_t* QKVb = (ushort_t*)p; p += (size_t)MTOT * NQKV * 2;
  ushort_t* Xb   = (ushort_t*)p; p += (size_t)MTOT * HIDDEN * 2;  // reused as Ab
  ushort_t* WT   = (ushort_t*)p; p += (size_t)NQKV * HIDDEN * 2;
  ushort_t* WoT  = (ushort_t*)p; p += (size_t)HIDDEN * HIDDEN * 2;
  ushort_t* Vt   = (ushort_t*)p; p += (size_t)HD * MTOT * 2;
  ushort_t* Ab = Xb;  // X consumed by QKV GEMM before flash writes Ab

  // fused preprocessing (mask flags, cvt, weight transposes, bias)
  prep_kernel<<<PREP_NB, 256, 0, stream>>>(
      X, Xb, Wq, Wk, Wv, WT, Wo, WoT, mask, flags, bq, bk, bv, biasQKV);

  // QKV projection: M=4096 (16 m-tiles), N=2304 (9 n-tiles) -> 144 blocks;
  // epilogue also writes Vt (fused V-transpose; transpose_v kernel removed)
  gemm_mfma8<0, 1><<<dim3((MTOT / 256) * (NQKV / 256)), 512, 0, stream>>>(
      Xb, WT, biasQKV, QKVb, Vt, MTOT, NQKV, HIDDEN, (MTOT / 256) / 8);
  flash_mfma<<<dim3(SEQ / 128, HEADS, BSZ), 256, 0, stream>>>(
      QKVb, Vt, mask, flags, Ab);
  // O projection: M=4096 (16 m-tiles), N=2048 (8 n-tiles) -> 128 blocks
  gemm_mfma8<1, 0><<<dim3((MTOT / 256) * (HIDDEN / 256)), 512, 0, stream>>>(
      Ab, WoT, bo, out, nullptr, MTOT, HIDDEN, HIDDEN, (MTOT / 256) / 8);
}

// Round 11
// 337.990 us; speedup vs baseline: 1.0733x; 1.0733x over previous
//
#include <hip/hip_runtime.h>
#include <cstdint>
#include <cstddef>

#define HIDDEN 2048
#define HEADS 16
#define HD 128
#define BSZ 2
#define SEQ 2048
#define MTOT (BSZ * SEQ)        // 4096
#define NQKV (HIDDEN + 2 * HD)  // 2304
#define SL2E 0.12751743f        // (1/sqrt(128)) * log2(e)

typedef unsigned short ushort_t;
typedef __attribute__((ext_vector_type(8))) __bf16 bf16x8;
typedef __attribute__((ext_vector_type(4))) float f32x4;
typedef __attribute__((ext_vector_type(16))) float f32x16;

typedef __attribute__((address_space(3))) unsigned int as3_u32;
typedef __attribute__((address_space(1))) const unsigned int as1_u32;

// fp32 -> bf16 round-to-nearest-even
__device__ __forceinline__ ushort_t f2bf(float x) {
  union { float f; unsigned u; } v; v.f = x;
  unsigned r = v.u + 0x7fffu + ((v.u >> 16) & 1u);
  return (ushort_t)(r >> 16);
}
// pack two fp32 -> bf16x2 (truncation; bias cancels in normalized softmax)
__device__ __forceinline__ unsigned pk_bf16(float a, float b) {
  union { float f; unsigned u; } x, y; x.f = a; y.f = b;
  return (x.u >> 16) | (y.u & 0xFFFF0000u);
}

// async global->LDS, 16B per lane; lds dst is wave-uniform (HW adds lane*16)
__device__ __forceinline__ void gld16(const void* g, void* lds) {
  __builtin_amdgcn_global_load_lds((as1_u32*)g, (as3_u32*)lds, 16, 0, 0);
}

// ---------------------------------------------------------------------------
// Fused preprocessing (proven in round 9; biasQKV gets 16 KB — NQKV floats
// = 9216 B; the old 4096 B allocation was the rounds-6-8 corruption bug).
// Block ranges (all 256-thread, branch is block-uniform):
//   [0, NM)              mask_flags   per (b,q128,k64) 0/1/2
//   [NM, +N0)            cvt_bf16     X f32 -> Xb bf16 (float4/ushort4)
//   [.., +N1)            cvtT_qkv     Wq|Wk|Wv -> WT (2304x2048), Wq * SL2E
//   [.., +N2)            cvtT         Wo -> WoT (2048x2048)
//   [.., +N4)            concat_bias  biasQKV (Q-part * SL2E)
// ---------------------------------------------------------------------------
#define PREP_NM (32 * 16 * BSZ)                  // 1024
#define PREP_N0 (MTOT * HIDDEN / 4 / 256)        // 8192
#define PREP_N1 ((NQKV / 32) * (HIDDEN / 32))    // 4608
#define PREP_N2 ((HIDDEN / 32) * (HIDDEN / 32))  // 4096
#define PREP_N4 ((NQKV + 255) / 256)             // 9
#define PREP_NB (PREP_NM + PREP_N0 + PREP_N1 + PREP_N2 + PREP_N4)

__global__ __launch_bounds__(256) void prep_kernel(
    const float* __restrict__ X, ushort_t* __restrict__ Xb,
    const float* __restrict__ Wq, const float* __restrict__ Wk,
    const float* __restrict__ Wv, ushort_t* __restrict__ WT,
    const float* __restrict__ Wo, ushort_t* __restrict__ WoT,
    const int* __restrict__ mask, int* __restrict__ flags,
    const float* __restrict__ bq, const float* __restrict__ bk,
    const float* __restrict__ bv, float* __restrict__ biasQKV) {
  __shared__ float tileF[32][36];
  __shared__ int sAO[8];
  const int t = threadIdx.x;
  int j = blockIdx.x;

  if (j < PREP_NM) {  // ---- mask_flags (long-pole blocks first) ----
    const int kt = j & 31, qt = (j >> 5) & 15, b = j >> 9;
    int allv = 1, anyv = 0;
    const size_t base = (size_t)b * SEQ * SEQ + (size_t)qt * 128 * SEQ + kt * 64;
    for (int i = t; i < 2048; i += 256) {  // 128 rows x 16 int4
      const int row = i >> 4, c4 = (i & 15) << 2;
      const int4 v = *(const int4*)(mask + base + (size_t)row * SEQ + c4);
      const int nz = (v.x != 0) & (v.y != 0) & (v.z != 0) & (v.w != 0);
      const int nzany = (v.x != 0) | (v.y != 0) | (v.z != 0) | (v.w != 0);
      allv &= nz; anyv |= nzany;
    }
    const int wAll = __all(allv), wAny = __any(anyv);
    if ((t & 63) == 0) { sAO[t >> 6] = wAll; sAO[4 + (t >> 6)] = wAny; }
    __syncthreads();
    if (t == 0) {
      const int A = sAO[0] & sAO[1] & sAO[2] & sAO[3];
      const int O = sAO[4] | sAO[5] | sAO[6] | sAO[7];
      flags[(b * 16 + qt) * 32 + kt] = A ? 2 : (O ? 1 : 0);
    }
    return;
  }
  j -= PREP_NM;

  if (j < PREP_N0) {  // ---- cvt_bf16 (exact coverage, no bounds check) ----
    const int i = j * 256 + t;
    float4 v = ((const float4*)X)[i];
    ushort4 o;
    o.x = f2bf(v.x); o.y = f2bf(v.y); o.z = f2bf(v.z); o.w = f2bf(v.w);
    ((ushort4*)Xb)[i] = o;
    return;
  }
  j -= PREP_N0;

  if (j < PREP_N1) {  // ---- cvtT_qkv ----
    const int nb = (j % (NQKV / 32)) * 32, kb = (j / (NQKV / 32)) * 32;
    const float* W; int N, nc; float scale;
    if (nb < HIDDEN)           { W = Wq; N = HIDDEN; nc = nb;               scale = SL2E; }
    else if (nb < HIDDEN + HD) { W = Wk; N = HD;     nc = nb - HIDDEN;      scale = 1.f; }
    else                       { W = Wv; N = HD;     nc = nb - HIDDEN - HD; scale = 1.f; }
    {
      int row = t >> 3, c4 = (t & 7) << 2;
      float4 v = *(const float4*)(W + (size_t)(kb + row) * N + nc + c4);
      tileF[row][c4] = v.x * scale; tileF[row][c4 + 1] = v.y * scale;
      tileF[row][c4 + 2] = v.z * scale; tileF[row][c4 + 3] = v.w * scale;
    }
    __syncthreads();
    {
      int nl = t >> 3, k4 = (t & 7) << 2;
      ushort4 o;
      o.x = f2bf(tileF[k4 + 0][nl]); o.y = f2bf(tileF[k4 + 1][nl]);
      o.z = f2bf(tileF[k4 + 2][nl]); o.w = f2bf(tileF[k4 + 3][nl]);
      *(ushort4*)(WT + (size_t)(nb + nl) * HIDDEN + kb + k4) = o;
    }
    return;
  }
  j -= PREP_N1;

  if (j < PREP_N2) {  // ---- cvtT (Wo -> WoT), K=N=HIDDEN ----
    const int nb = (j % (HIDDEN / 32)) * 32, kb = (j / (HIDDEN / 32)) * 32;
    {
      int row = t >> 3, c4 = (t & 7) << 2;
      float4 v = *(const float4*)(Wo + (size_t)(kb + row) * HIDDEN + nb + c4);
      tileF[row][c4] = v.x; tileF[row][c4 + 1] = v.y;
      tileF[row][c4 + 2] = v.z; tileF[row][c4 + 3] = v.w;
    }
    __syncthreads();
    {
      int nl = t >> 3, k4 = (t & 7) << 2;
      ushort4 o;
      o.x = f2bf(tileF[k4 + 0][nl]); o.y = f2bf(tileF[k4 + 1][nl]);
      o.z = f2bf(tileF[k4 + 2][nl]); o.w = f2bf(tileF[k4 + 3][nl]);
      *(ushort4*)(WoT + (size_t)(nb + nl) * HIDDEN + kb + k4) = o;
    }
    return;
  }
  j -= PREP_N2;

  {  // ---- concat_bias ----
    const int i = j * 256 + t;
    if (i < NQKV)
      biasQKV[i] = (i < HIDDEN) ? bq[i] * SL2E
                 : (i < HIDDEN + HD ? bk[i - HIDDEN] : bv[i - HIDDEN - HD]);
  }
}

// ---------------------------------------------------------------------------
// bf16 MFMA GEMM, 2-phase 128x128 double-buffered — the proven-best structure
// at these shapes (pair ≈ 123 us by r10−r9 differencing; the 256² 8-phase
// template measured 84 us/GEMM with MfmaUtil 17% across three variants:
// its grid (144/128 blocks) leaves >44% of CUs idle at 1 block/CU, and its
// per-block rate never exceeded 52% of the reference — line closed).
// FUSEV: QKV-GEMM epilogue also scatter-writes the V slice transposed into
// Vt (validated in r10), replacing the separate transpose_v kernel.
// ---------------------------------------------------------------------------
template <int OUTF32, int FUSEV>
__global__ __launch_bounds__(256) void gemm_mfma(
    const ushort_t* __restrict__ A, const ushort_t* __restrict__ Bt,
    const float* __restrict__ bias, void* __restrict__ C,
    ushort_t* __restrict__ Vt, int M, int N, int K, int nm_per_xcd) {
  __shared__ ushort_t As[2][128 * 64];
  __shared__ ushort_t Bs[2][128 * 64];
  const int t = threadIdx.x;
  const int w = t >> 6, l = t & 63;
  const int id = blockIdx.x;
  const int xcd = id & 7, j = id >> 3;
  const int mt = xcd * nm_per_xcd + (j % nm_per_xcd);
  const int nt = j / nm_per_xcd;
  const int mb = mt * 128, nb = nt * 128;
  const int wm = (w >> 1) * 64, wn = (w & 1) * 64;
  const int fl = l & 15, g = l >> 4;
  const int srow = l >> 3, cphys = l & 7;

  f32x4 acc[4][4];
#pragma unroll
  for (int i = 0; i < 4; ++i)
#pragma unroll
    for (int jj = 0; jj < 4; ++jj) acc[i][jj] = (f32x4){0.f, 0.f, 0.f, 0.f};

#pragma unroll
  for (int jj = 0; jj < 4; ++jj) {
    const int inst = w * 4 + jj;
    const int row = inst * 8 + srow;
    const int clog = cphys ^ (row & 7);
    gld16(A + (size_t)(mb + row) * K + clog * 8, &As[0][inst * 512]);
    gld16(Bt + (size_t)(nb + row) * K + clog * 8, &Bs[0][inst * 512]);
  }

  int cur = 0;
  for (int k0 = 0; k0 < K; k0 += 64) {
    __syncthreads();
    if (k0 + 64 < K) {
#pragma unroll
      for (int jj = 0; jj < 4; ++jj) {
        const int inst = w * 4 + jj;
        const int row = inst * 8 + srow;
        const int clog = cphys ^ (row & 7);
        gld16(A + (size_t)(mb + row) * K + k0 + 64 + clog * 8,
              &As[cur ^ 1][inst * 512]);
        gld16(Bt + (size_t)(nb + row) * K + k0 + 64 + clog * 8,
              &Bs[cur ^ 1][inst * 512]);
      }
    }
    const ushort_t* Ac = &As[cur][0];
    const ushort_t* Bc = &Bs[cur][0];
#pragma unroll
    for (int s = 0; s < 2; ++s) {
      bf16x8 af[4], bfr[4];
#pragma unroll
      for (int i = 0; i < 4; ++i) {
        const int m = wm + i * 16 + fl;
        af[i] = *(const bf16x8*)&Ac[m * 64 + (((s << 2) + g) ^ (m & 7)) * 8];
        const int n = wn + i * 16 + fl;
        bfr[i] = *(const bf16x8*)&Bc[n * 64 + (((s << 2) + g) ^ (n & 7)) * 8];
      }
#pragma unroll
      for (int i = 0; i < 4; ++i)
#pragma unroll
        for (int jj = 0; jj < 4; ++jj)
          acc[i][jj] = __builtin_amdgcn_mfma_f32_16x16x32_bf16(
              af[i], bfr[jj], acc[i][jj], 0, 0, 0);
    }
    cur ^= 1;
  }

  // epilogue (+ fused V-transpose write for the QKV GEMM: V cols >= 2176)
#pragma unroll
  for (int jj = 0; jj < 4; ++jj) {
    const int col = nb + wn + jj * 16 + fl;
    const float bv = bias[col];
    const int dv = col - (HIDDEN + HD);
#pragma unroll
    for (int i = 0; i < 4; ++i) {
      const int row0 = mb + wm + i * 16 + g * 4;
#pragma unroll
      for (int r = 0; r < 4; ++r) {
        const float val = acc[i][jj][r] + bv;
        if (OUTF32) {
          ((float*)C)[(size_t)(row0 + r) * N + col] = val;
        } else {
          const ushort_t bb = f2bf(val);
          ((ushort_t*)C)[(size_t)(row0 + r) * N + col] = bb;
          if (FUSEV && dv >= 0)
            Vt[(size_t)dv * MTOT + row0 + r] = bb;
        }
      }
    }
  }
}

// ---------------------------------------------------------------------------
// MFMA flash attention (unchanged: 82 us, 0 bank conflicts, 2 blocks/CU).
// ---------------------------------------------------------------------------
__global__ __launch_bounds__(256, 2) void flash_mfma(
    const ushort_t* __restrict__ QKV,  // (4096, 2304) bf16; Q pre-scaled
    const ushort_t* __restrict__ Vt,   // (128, 4096) bf16
    const int* __restrict__ mask,      // (B, S, S)
    const int* __restrict__ flags,     // (B, 16, 32)
    ushort_t* __restrict__ Ab)         // (4096, 2048) bf16
{
  __shared__ ushort_t Kbuf[2][64 * 128];  // 32 KB: key rows x 128 k-dim
  __shared__ ushort_t Vbuf[2][64 * 128];  // 32 KB: paired-d rows x (2x8) chunks

  const int qt = blockIdx.x, h = blockIdx.y, b = blockIdx.z;
  const int t = threadIdx.x, w = t >> 6, l = t & 63;
  const int q31 = l & 31, hi = l >> 5;
  const int qbase = qt * 128;
  const int qrow = qbase + w * 32 + q31;  // within-batch q row (B-col index)

  // Q as B-fragments: col=q31, k = ks*16 + hi*8 + j (exp2 domain, pre-scaled)
  bf16x8 qf[8];
#pragma unroll
  for (int ks = 0; ks < 8; ++ks)
    qf[ks] = *(const bf16x8*)(QKV + (size_t)(b * SEQ + qrow) * NQKV + h * HD +
                              ks * 16 + hi * 8);

  // ones B-frag for l: B[col=q31][k] = (q31==0) ? 1.0 : 0
  bf16x8 onesf;
  {
    const ushort_t ov = (q31 == 0) ? (ushort_t)0x3F80 : (ushort_t)0;
#pragma unroll
    for (int jj = 0; jj < 8; ++jj) ((ushort_t*)&onesf)[jj] = ov;
  }

  // prologue: prefetch K(0),V(0) -> buffer 0
#pragma unroll
  for (int j = 0; j < 4; ++j) {
    const int inst = w * 4 + j;
    // K: 256B rows; phys chunk (l&15) holds logical (l&15)^(krow&15)
    const int krow = inst * 4 + (l >> 4);
    const int ck = (l & 15) ^ (krow & 15);
    gld16(QKV + (size_t)(b * SEQ + krow) * NQKV + HIDDEN + ck * 8,
          &Kbuf[0][inst * 512]);
    // V: LDS row r holds d=2r,2r+1; phys p = clog ^ (r&15), clog=(d&1)*8+kc
    const int vr = inst * 4 + (l >> 4);
    const int clog = (l & 15) ^ (vr & 15);
    const int d = 2 * vr + (clog >> 3);
    gld16(Vt + (size_t)d * MTOT + b * SEQ + (clog & 7) * 8,
          &Vbuf[0][inst * 512]);
  }

  const size_t mbase = (size_t)b * SEQ * SEQ;

  f32x16 oacc[4], lacc;
#pragma unroll
  for (int d = 0; d < 4; ++d)
#pragma unroll
    for (int r = 0; r < 16; ++r) oacc[d][r] = 0.f;
#pragma unroll
  for (int r = 0; r < 16; ++r) lacc[r] = 0.f;

  int cur = 0;
  for (int kt = 0; kt < SEQ / 64; ++kt) {
    const int kbase = kt * 64;
    const int flag = flags[((b * 16 + qt) << 5) + kt];  // block-uniform
    __syncthreads();  // buf[cur] DMAs drained; prev tile done with buf[cur^1]

    // prefetch K(kt+1), V(kt+1) -> buf[cur^1] (clamped on last tile)
    {
      const int knb = (kt + 1 < SEQ / 64) ? (kbase + 64) : kbase;
#pragma unroll
      for (int j = 0; j < 4; ++j) {
        const int inst = w * 4 + j;
        const int krow = inst * 4 + (l >> 4);
        const int ck = (l & 15) ^ (krow & 15);
        gld16(QKV + (size_t)(b * SEQ + knb + krow) * NQKV + HIDDEN + ck * 8,
              &Kbuf[cur ^ 1][inst * 512]);
        const int vr = inst * 4 + (l >> 4);
        const int clog = (l & 15) ^ (vr & 15);
        const int d = 2 * vr + (clog >> 3);
        gld16(Vt + (size_t)d * MTOT + b * SEQ + knb + (clog & 7) * 8,
              &Vbuf[cur ^ 1][inst * 512]);
      }
    }

    // ---- S^T = K·Q^T from Kbuf[cur]: A = K rows (key), B = Q cols (q) ----
    const ushort_t* Kc = &Kbuf[cur][0];
    f32x16 sc[2];
#pragma unroll
    for (int kk = 0; kk < 2; ++kk)
#pragma unroll
      for (int r = 0; r < 16; ++r) sc[kk][r] = 0.f;

    __builtin_amdgcn_s_setprio(1);
#pragma unroll
    for (int ks = 0; ks < 8; ++ks)
#pragma unroll
      for (int kk = 0; kk < 2; ++kk) {
        const int key = kk * 32 + q31;  // A-row = lane&31
        const bf16x8 kf = *(const bf16x8*)&Kc[key * 128 +
                                              (((ks << 1) + hi) ^ (key & 15)) * 8];
        sc[kk] = __builtin_amdgcn_mfma_f32_32x32x16_bf16(kf, qf[ks], sc[kk],
                                                         0, 0, 0);
      }
    __builtin_amdgcn_s_setprio(0);

    if (flag != 2) {  // mixed/empty tile: per-element mask fallback
#pragma unroll
      for (int kk = 0; kk < 2; ++kk)
#pragma unroll
        for (int r = 0; r < 16; ++r) {
          const int key = kbase + kk * 32 + (r & 3) + ((r >> 2) << 3) + (hi << 2);
          if (!mask[mbase + (size_t)qrow * SEQ + key]) sc[kk][r] = -1e30f;
        }
    }

    // ---- P = exp2(S^T); pack bf16; permlane32_swap -> PA A-frags in regs ----
    bf16x8 pa[4];
#pragma unroll
    for (int kk = 0; kk < 2; ++kk) {
      float pv[16];
#pragma unroll
      for (int r = 0; r < 16; ++r) pv[r] = __builtin_amdgcn_exp2f(sc[kk][r]);
#pragma unroll
      for (int half = 0; half < 2; ++half) {
        const int bs = half * 8;
        unsigned a0 = pk_bf16(pv[bs + 0], pv[bs + 1]);
        unsigned a1 = pk_bf16(pv[bs + 2], pv[bs + 3]);
        unsigned b0 = pk_bf16(pv[bs + 4], pv[bs + 5]);
        unsigned b1 = pk_bf16(pv[bs + 6], pv[bs + 7]);
        asm("v_permlane32_swap_b32 %0, %1" : "+v"(a0), "+v"(b0));
        asm("v_permlane32_swap_b32 %0, %1" : "+v"(a1), "+v"(b1));
        union { unsigned u[4]; bf16x8 v; } uu;
        uu.u[0] = a0; uu.u[1] = a1; uu.u[2] = b0; uu.u[3] = b1;
        pa[kk * 2 + half] = uu.v;
      }
    }

    // ---- O += P·V (B-frags from Vbuf[cur], paired-row layout); l += P·ones --
    const ushort_t* Vc = &Vbuf[cur][0];
    __builtin_amdgcn_s_setprio(1);
#pragma unroll
    for (int ks = 0; ks < 4; ++ks) {
#pragma unroll
      for (int dt = 0; dt < 4; ++dt) {
        const int d = dt * 32 + q31;  // B-col = lane&31
        const int vr = d >> 1;
        const int clog = ((d & 1) << 3) + (ks << 1) + hi;
        const bf16x8 vf =
            *(const bf16x8*)&Vc[vr * 128 + (clog ^ (vr & 15)) * 8];
        oacc[dt] = __builtin_amdgcn_mfma_f32_32x32x16_bf16(pa[ks], vf,
                                                           oacc[dt], 0, 0, 0);
      }
      lacc = __builtin_amdgcn_mfma_f32_32x32x16_bf16(pa[ks], onesf, lacc,
                                                     0, 0, 0);
    }
    __builtin_amdgcn_s_setprio(0);
    cur ^= 1;
  }

  // ---- epilogue: l lives in col 0 (lanes 0 and 32); D row = q = crow ----
#pragma unroll
  for (int r = 0; r < 16; ++r) {
    const float ls = __shfl(lacc[r], l & 32, 64);
    const float invl = 1.0f / ls;
    const int row = b * SEQ + qbase + w * 32 + (r & 3) + ((r >> 2) << 3) +
                    (hi << 2);
#pragma unroll
    for (int dt = 0; dt < 4; ++dt)
      Ab[(size_t)row * HIDDEN + h * HD + dt * 32 + q31] =
          f2bf(oacc[dt][r] * invl);
  }
}

// ---------------------------------------------------------------------------
extern "C" void kernel_launch(void* const* d_in, const int* in_sizes, int n_in,
                              void* d_out, int out_size, void* d_ws, size_t ws_size,
                              hipStream_t stream) {
  const float* X  = (const float*)d_in[0];
  const int* mask = (const int*)d_in[1];
  const float* Wq = (const float*)d_in[2];
  const float* bq = (const float*)d_in[3];
  const float* Wk = (const float*)d_in[4];
  const float* bk = (const float*)d_in[5];
  const float* Wv = (const float*)d_in[6];
  const float* bv = (const float*)d_in[7];
  const float* Wo = (const float*)d_in[8];
  const float* bo = (const float*)d_in[9];
  float* out = (float*)d_out;

  char* p = (char*)d_ws;
  int* flags     = (int*)p;      p += BSZ * 16 * 32 * 4;   // 4 KB
  float* biasQKV = (float*)p;    p += 16384;  // NQKV floats = 9216 B; 16 KB reserved
  ushort_t* QKVb = (ushort_t*)p; p += (size_t)MTOT * NQKV * 2;
  ushort_t* Xb   = (ushort_t*)p; p += (size_t)MTOT * HIDDEN * 2;  // reused as Ab
  ushort_t* WT   = (ushort_t*)p; p += (size_t)NQKV * HIDDEN * 2;
  ushort_t* WoT  = (ushort_t*)p; p += (size_t)HIDDEN * HIDDEN * 2;
  ushort_t* Vt   = (ushort_t*)p; p += (size_t)HD * MTOT * 2;
  ushort_t* Ab = Xb;  // X consumed by QKV GEMM before flash writes Ab

  // fused preprocessing (mask flags, cvt, weight transposes, bias)
  prep_kernel<<<PREP_NB, 256, 0, stream>>>(
      X, Xb, Wq, Wk, Wv, WT, Wo, WoT, mask, flags, bq, bk, bv, biasQKV);

  // QKV projection: M=4096 (32 m-tiles), N=2304 (18 n-tiles); nm/8 = 4.
  // Epilogue also writes Vt (fused V-transpose; transpose_v kernel removed).
  gemm_mfma<0, 1><<<dim3((MTOT / 128) * (NQKV / 128)), 256, 0, stream>>>(
      Xb, WT, biasQKV, QKVb, Vt, MTOT, NQKV, HIDDEN, (MTOT / 128) / 8);
  flash_mfma<<<dim3(SEQ / 128, HEADS, BSZ), 256, 0, stream>>>(
      QKVb, Vt, mask, flags, Ab);
  // O projection: M=4096 (32 m-tiles), N=2048 (16 n-tiles)
  gemm_mfma<1, 0><<<dim3((MTOT / 128) * (HIDDEN / 128)), 256, 0, stream>>>(
      Ab, WoT, bo, out, nullptr, MTOT, HIDDEN, HIDDEN, (MTOT / 128) / 8);
}

// Round 12
// 313.866 us; speedup vs baseline: 1.1558x; 1.0769x over previous
//
#include <hip/hip_runtime.h>
#include <cstdint>
#include <cstddef>

#define HIDDEN 2048
#define HEADS 16
#define HD 128
#define BSZ 2
#define SEQ 2048
#define MTOT (BSZ * SEQ)        // 4096
#define NQKV (HIDDEN + 2 * HD)  // 2304
#define SL2E 0.12751743f        // (1/sqrt(128)) * log2(e)

typedef unsigned short ushort_t;
typedef __attribute__((ext_vector_type(8))) __bf16 bf16x8;
typedef __attribute__((ext_vector_type(4))) float f32x4;
typedef __attribute__((ext_vector_type(16))) float f32x16;

typedef __attribute__((address_space(3))) unsigned int as3_u32;
typedef __attribute__((address_space(1))) const unsigned int as1_u32;

// fp32 -> bf16 round-to-nearest-even
__device__ __forceinline__ ushort_t f2bf(float x) {
  union { float f; unsigned u; } v; v.f = x;
  unsigned r = v.u + 0x7fffu + ((v.u >> 16) & 1u);
  return (ushort_t)(r >> 16);
}
// pack two fp32 -> bf16x2 (truncation; bias cancels in normalized softmax)
__device__ __forceinline__ unsigned pk_bf16(float a, float b) {
  union { float f; unsigned u; } x, y; x.f = a; y.f = b;
  return (x.u >> 16) | (y.u & 0xFFFF0000u);
}

// async global->LDS, 16B per lane; lds dst is wave-uniform (HW adds lane*16)
__device__ __forceinline__ void gld16(const void* g, void* lds) {
  __builtin_amdgcn_global_load_lds((as1_u32*)g, (as3_u32*)lds, 16, 0, 0);
}

// ---------------------------------------------------------------------------
// Fused preprocessing (proven in round 9; biasQKV gets 16 KB — NQKV floats
// = 9216 B; the old 4096 B allocation was the rounds-6-8 corruption bug).
// Block ranges (all 256-thread, branch is block-uniform):
//   [0, NM)              mask_flags   per (b,q128,k64) 0/1/2
//   [NM, +N0)            cvt_bf16     X f32 -> Xb bf16 (float4/ushort4)
//   [.., +N1)            cvtT_qkv     Wq|Wk|Wv -> WT (2304x2048), Wq * SL2E
//   [.., +N2)            cvtT         Wo -> WoT (2048x2048)
//   [.., +N4)            concat_bias  biasQKV (Q-part * SL2E)
// ---------------------------------------------------------------------------
#define PREP_NM (32 * 16 * BSZ)                  // 1024
#define PREP_N0 (MTOT * HIDDEN / 4 / 256)        // 8192
#define PREP_N1 ((NQKV / 32) * (HIDDEN / 32))    // 4608
#define PREP_N2 ((HIDDEN / 32) * (HIDDEN / 32))  // 4096
#define PREP_N4 ((NQKV + 255) / 256)             // 9
#define PREP_NB (PREP_NM + PREP_N0 + PREP_N1 + PREP_N2 + PREP_N4)

__global__ __launch_bounds__(256) void prep_kernel(
    const float* __restrict__ X, ushort_t* __restrict__ Xb,
    const float* __restrict__ Wq, const float* __restrict__ Wk,
    const float* __restrict__ Wv, ushort_t* __restrict__ WT,
    const float* __restrict__ Wo, ushort_t* __restrict__ WoT,
    const int* __restrict__ mask, int* __restrict__ flags,
    const float* __restrict__ bq, const float* __restrict__ bk,
    const float* __restrict__ bv, float* __restrict__ biasQKV) {
  __shared__ float tileF[32][36];
  __shared__ int sAO[8];
  const int t = threadIdx.x;
  int j = blockIdx.x;

  if (j < PREP_NM) {  // ---- mask_flags (long-pole blocks first) ----
    const int kt = j & 31, qt = (j >> 5) & 15, b = j >> 9;
    int allv = 1, anyv = 0;
    const size_t base = (size_t)b * SEQ * SEQ + (size_t)qt * 128 * SEQ + kt * 64;
    for (int i = t; i < 2048; i += 256) {  // 128 rows x 16 int4
      const int row = i >> 4, c4 = (i & 15) << 2;
      const int4 v = *(const int4*)(mask + base + (size_t)row * SEQ + c4);
      const int nz = (v.x != 0) & (v.y != 0) & (v.z != 0) & (v.w != 0);
      const int nzany = (v.x != 0) | (v.y != 0) | (v.z != 0) | (v.w != 0);
      allv &= nz; anyv |= nzany;
    }
    const int wAll = __all(allv), wAny = __any(anyv);
    if ((t & 63) == 0) { sAO[t >> 6] = wAll; sAO[4 + (t >> 6)] = wAny; }
    __syncthreads();
    if (t == 0) {
      const int A = sAO[0] & sAO[1] & sAO[2] & sAO[3];
      const int O = sAO[4] | sAO[5] | sAO[6] | sAO[7];
      flags[(b * 16 + qt) * 32 + kt] = A ? 2 : (O ? 1 : 0);
    }
    return;
  }
  j -= PREP_NM;

  if (j < PREP_N0) {  // ---- cvt_bf16 (exact coverage, no bounds check) ----
    const int i = j * 256 + t;
    float4 v = ((const float4*)X)[i];
    ushort4 o;
    o.x = f2bf(v.x); o.y = f2bf(v.y); o.z = f2bf(v.z); o.w = f2bf(v.w);
    ((ushort4*)Xb)[i] = o;
    return;
  }
  j -= PREP_N0;

  if (j < PREP_N1) {  // ---- cvtT_qkv ----
    const int nb = (j % (NQKV / 32)) * 32, kb = (j / (NQKV / 32)) * 32;
    const float* W; int N, nc; float scale;
    if (nb < HIDDEN)           { W = Wq; N = HIDDEN; nc = nb;               scale = SL2E; }
    else if (nb < HIDDEN + HD) { W = Wk; N = HD;     nc = nb - HIDDEN;      scale = 1.f; }
    else                       { W = Wv; N = HD;     nc = nb - HIDDEN - HD; scale = 1.f; }
    {
      int row = t >> 3, c4 = (t & 7) << 2;
      float4 v = *(const float4*)(W + (size_t)(kb + row) * N + nc + c4);
      tileF[row][c4] = v.x * scale; tileF[row][c4 + 1] = v.y * scale;
      tileF[row][c4 + 2] = v.z * scale; tileF[row][c4 + 3] = v.w * scale;
    }
    __syncthreads();
    {
      int nl = t >> 3, k4 = (t & 7) << 2;
      ushort4 o;
      o.x = f2bf(tileF[k4 + 0][nl]); o.y = f2bf(tileF[k4 + 1][nl]);
      o.z = f2bf(tileF[k4 + 2][nl]); o.w = f2bf(tileF[k4 + 3][nl]);
      *(ushort4*)(WT + (size_t)(nb + nl) * HIDDEN + kb + k4) = o;
    }
    return;
  }
  j -= PREP_N1;

  if (j < PREP_N2) {  // ---- cvtT (Wo -> WoT), K=N=HIDDEN ----
    const int nb = (j % (HIDDEN / 32)) * 32, kb = (j / (HIDDEN / 32)) * 32;
    {
      int row = t >> 3, c4 = (t & 7) << 2;
      float4 v = *(const float4*)(Wo + (size_t)(kb + row) * HIDDEN + nb + c4);
      tileF[row][c4] = v.x; tileF[row][c4 + 1] = v.y;
      tileF[row][c4 + 2] = v.z; tileF[row][c4 + 3] = v.w;
    }
    __syncthreads();
    {
      int nl = t >> 3, k4 = (t & 7) << 2;
      ushort4 o;
      o.x = f2bf(tileF[k4 + 0][nl]); o.y = f2bf(tileF[k4 + 1][nl]);
      o.z = f2bf(tileF[k4 + 2][nl]); o.w = f2bf(tileF[k4 + 3][nl]);
      *(ushort4*)(WoT + (size_t)(nb + nl) * HIDDEN + kb + k4) = o;
    }
    return;
  }
  j -= PREP_N2;

  {  // ---- concat_bias ----
    const int i = j * 256 + t;
    if (i < NQKV)
      biasQKV[i] = (i < HIDDEN) ? bq[i] * SL2E
                 : (i < HIDDEN + HD ? bk[i - HIDDEN] : bv[i - HIDDEN - HD]);
  }
}

// ---------------------------------------------------------------------------
// bf16 MFMA GEMM, 2-phase 128x128 double-buffered (proven structure; 460 TF
// at these shapes — matches the reference shape-curve for this template).
// FUSEV round-18 fix: r11's per-element Vt scatter (2B stores at 8KB stride)
// cost ~20us in write-sector amplification. Now the V tile (exactly n-tile
// nb==2176, 32 of 576 blocks) is transposed through LDS after the K-loop
// (As/Bs dead -> reuse via Smem carving; pad 132 keeps ushort4 alignment)
// and written to Vt as coalesced ushort4 rows (256B per half-wave).
// ---------------------------------------------------------------------------
template <int OUTF32, int FUSEV>
__global__ __launch_bounds__(256) void gemm_mfma(
    const ushort_t* __restrict__ A, const ushort_t* __restrict__ Bt,
    const float* __restrict__ bias, void* __restrict__ C,
    ushort_t* __restrict__ Vt, int M, int N, int K, int nm_per_xcd) {
  __shared__ ushort_t Smem[4 * 128 * 64];  // 64 KB: As[2] | Bs[2]
  ushort_t (*As)[128 * 64] = reinterpret_cast<ushort_t(*)[128 * 64]>(Smem);
  ushort_t (*Bs)[128 * 64] =
      reinterpret_cast<ushort_t(*)[128 * 64]>(Smem + 2 * 128 * 64);
  const int t = threadIdx.x;
  const int w = t >> 6, l = t & 63;
  const int id = blockIdx.x;
  const int xcd = id & 7, j = id >> 3;
  const int mt = xcd * nm_per_xcd + (j % nm_per_xcd);
  const int nt = j / nm_per_xcd;
  const int mb = mt * 128, nb = nt * 128;
  const int wm = (w >> 1) * 64, wn = (w & 1) * 64;
  const int fl = l & 15, g = l >> 4;
  const int srow = l >> 3, cphys = l & 7;

  f32x4 acc[4][4];
#pragma unroll
  for (int i = 0; i < 4; ++i)
#pragma unroll
    for (int jj = 0; jj < 4; ++jj) acc[i][jj] = (f32x4){0.f, 0.f, 0.f, 0.f};

#pragma unroll
  for (int jj = 0; jj < 4; ++jj) {
    const int inst = w * 4 + jj;
    const int row = inst * 8 + srow;
    const int clog = cphys ^ (row & 7);
    gld16(A + (size_t)(mb + row) * K + clog * 8, &As[0][inst * 512]);
    gld16(Bt + (size_t)(nb + row) * K + clog * 8, &Bs[0][inst * 512]);
  }

  int cur = 0;
  for (int k0 = 0; k0 < K; k0 += 64) {
    __syncthreads();
    if (k0 + 64 < K) {
#pragma unroll
      for (int jj = 0; jj < 4; ++jj) {
        const int inst = w * 4 + jj;
        const int row = inst * 8 + srow;
        const int clog = cphys ^ (row & 7);
        gld16(A + (size_t)(mb + row) * K + k0 + 64 + clog * 8,
              &As[cur ^ 1][inst * 512]);
        gld16(Bt + (size_t)(nb + row) * K + k0 + 64 + clog * 8,
              &Bs[cur ^ 1][inst * 512]);
      }
    }
    const ushort_t* Ac = &As[cur][0];
    const ushort_t* Bc = &Bs[cur][0];
#pragma unroll
    for (int s = 0; s < 2; ++s) {
      bf16x8 af[4], bfr[4];
#pragma unroll
      for (int i = 0; i < 4; ++i) {
        const int m = wm + i * 16 + fl;
        af[i] = *(const bf16x8*)&Ac[m * 64 + (((s << 2) + g) ^ (m & 7)) * 8];
        const int n = wn + i * 16 + fl;
        bfr[i] = *(const bf16x8*)&Bc[n * 64 + (((s << 2) + g) ^ (n & 7)) * 8];
      }
#pragma unroll
      for (int i = 0; i < 4; ++i)
#pragma unroll
        for (int jj = 0; jj < 4; ++jj)
          acc[i][jj] = __builtin_amdgcn_mfma_f32_16x16x32_bf16(
              af[i], bfr[jj], acc[i][jj], 0, 0, 0);
    }
    cur ^= 1;
  }

  // V-transpose staging happens only for the QKV GEMM's V n-tile (nb==2176);
  // branch is block-uniform.
  const bool dofv = FUSEV && (nb == HIDDEN + HD);
  if (dofv) __syncthreads();  // all waves done reading As/Bs; Smem reusable

  // epilogue: C stores (+ LDS-staged V tile for dofv blocks)
#pragma unroll
  for (int jj = 0; jj < 4; ++jj) {
    const int col = nb + wn + jj * 16 + fl;
    const float bv = bias[col];
#pragma unroll
    for (int i = 0; i < 4; ++i) {
      const int row0 = mb + wm + i * 16 + g * 4;
#pragma unroll
      for (int r = 0; r < 4; ++r) {
        const float val = acc[i][jj][r] + bv;
        if (OUTF32) {
          ((float*)C)[(size_t)(row0 + r) * N + col] = val;
        } else {
          const ushort_t bb = f2bf(val);
          ((ushort_t*)C)[(size_t)(row0 + r) * N + col] = bb;
          if (dofv) {
            // Vs[col_local][row_local], pad 132 (keeps 8B alignment for the
            // coalesced ushort4 read-out; ~4-way write conflicts, tail-only)
            const int cl = wn + jj * 16 + fl;
            const int rl = row0 - mb + r;
            Smem[cl * 132 + rl] = bb;
          }
        }
      }
    }
  }

  if (dofv) {
    __syncthreads();
    // coalesced write-out: 128 d-rows x 128 cols; each thread 16x ushort4
    const int c4 = (t & 31) * 4;
#pragma unroll
    for (int k = 0; k < 16; ++k) {
      const int d = k * 8 + (t >> 5);
      const ushort4 v = *(const ushort4*)&Smem[d * 132 + c4];
      *(ushort4*)(Vt + (size_t)d * MTOT + mb + c4) = v;
    }
  }
}

// ---------------------------------------------------------------------------
// MFMA flash attention (unchanged: 82 us, 0 bank conflicts, 2 blocks/CU).
// ---------------------------------------------------------------------------
__global__ __launch_bounds__(256, 2) void flash_mfma(
    const ushort_t* __restrict__ QKV,  // (4096, 2304) bf16; Q pre-scaled
    const ushort_t* __restrict__ Vt,   // (128, 4096) bf16
    const int* __restrict__ mask,      // (B, S, S)
    const int* __restrict__ flags,     // (B, 16, 32)
    ushort_t* __restrict__ Ab)         // (4096, 2048) bf16
{
  __shared__ ushort_t Kbuf[2][64 * 128];  // 32 KB: key rows x 128 k-dim
  __shared__ ushort_t Vbuf[2][64 * 128];  // 32 KB: paired-d rows x (2x8) chunks

  const int qt = blockIdx.x, h = blockIdx.y, b = blockIdx.z;
  const int t = threadIdx.x, w = t >> 6, l = t & 63;
  const int q31 = l & 31, hi = l >> 5;
  const int qbase = qt * 128;
  const int qrow = qbase + w * 32 + q31;  // within-batch q row (B-col index)

  // Q as B-fragments: col=q31, k = ks*16 + hi*8 + j (exp2 domain, pre-scaled)
  bf16x8 qf[8];
#pragma unroll
  for (int ks = 0; ks < 8; ++ks)
    qf[ks] = *(const bf16x8*)(QKV + (size_t)(b * SEQ + qrow) * NQKV + h * HD +
                              ks * 16 + hi * 8);

  // ones B-frag for l: B[col=q31][k] = (q31==0) ? 1.0 : 0
  bf16x8 onesf;
  {
    const ushort_t ov = (q31 == 0) ? (ushort_t)0x3F80 : (ushort_t)0;
#pragma unroll
    for (int jj = 0; jj < 8; ++jj) ((ushort_t*)&onesf)[jj] = ov;
  }

  // prologue: prefetch K(0),V(0) -> buffer 0
#pragma unroll
  for (int j = 0; j < 4; ++j) {
    const int inst = w * 4 + j;
    // K: 256B rows; phys chunk (l&15) holds logical (l&15)^(krow&15)
    const int krow = inst * 4 + (l >> 4);
    const int ck = (l & 15) ^ (krow & 15);
    gld16(QKV + (size_t)(b * SEQ + krow) * NQKV + HIDDEN + ck * 8,
          &Kbuf[0][inst * 512]);
    // V: LDS row r holds d=2r,2r+1; phys p = clog ^ (r&15), clog=(d&1)*8+kc
    const int vr = inst * 4 + (l >> 4);
    const int clog = (l & 15) ^ (vr & 15);
    const int d = 2 * vr + (clog >> 3);
    gld16(Vt + (size_t)d * MTOT + b * SEQ + (clog & 7) * 8,
          &Vbuf[0][inst * 512]);
  }

  const size_t mbase = (size_t)b * SEQ * SEQ;

  f32x16 oacc[4], lacc;
#pragma unroll
  for (int d = 0; d < 4; ++d)
#pragma unroll
    for (int r = 0; r < 16; ++r) oacc[d][r] = 0.f;
#pragma unroll
  for (int r = 0; r < 16; ++r) lacc[r] = 0.f;

  int cur = 0;
  for (int kt = 0; kt < SEQ / 64; ++kt) {
    const int kbase = kt * 64;
    const int flag = flags[((b * 16 + qt) << 5) + kt];  // block-uniform
    __syncthreads();  // buf[cur] DMAs drained; prev tile done with buf[cur^1]

    // prefetch K(kt+1), V(kt+1) -> buf[cur^1] (clamped on last tile)
    {
      const int knb = (kt + 1 < SEQ / 64) ? (kbase + 64) : kbase;
#pragma unroll
      for (int j = 0; j < 4; ++j) {
        const int inst = w * 4 + j;
        const int krow = inst * 4 + (l >> 4);
        const int ck = (l & 15) ^ (krow & 15);
        gld16(QKV + (size_t)(b * SEQ + knb + krow) * NQKV + HIDDEN + ck * 8,
              &Kbuf[cur ^ 1][inst * 512]);
        const int vr = inst * 4 + (l >> 4);
        const int clog = (l & 15) ^ (vr & 15);
        const int d = 2 * vr + (clog >> 3);
        gld16(Vt + (size_t)d * MTOT + b * SEQ + knb + (clog & 7) * 8,
              &Vbuf[cur ^ 1][inst * 512]);
      }
    }

    // ---- S^T = K·Q^T from Kbuf[cur]: A = K rows (key), B = Q cols (q) ----
    const ushort_t* Kc = &Kbuf[cur][0];
    f32x16 sc[2];
#pragma unroll
    for (int kk = 0; kk < 2; ++kk)
#pragma unroll
      for (int r = 0; r < 16; ++r) sc[kk][r] = 0.f;

    __builtin_amdgcn_s_setprio(1);
#pragma unroll
    for (int ks = 0; ks < 8; ++ks)
#pragma unroll
      for (int kk = 0; kk < 2; ++kk) {
        const int key = kk * 32 + q31;  // A-row = lane&31
        const bf16x8 kf = *(const bf16x8*)&Kc[key * 128 +
                                              (((ks << 1) + hi) ^ (key & 15)) * 8];
        sc[kk] = __builtin_amdgcn_mfma_f32_32x32x16_bf16(kf, qf[ks], sc[kk],
                                                         0, 0, 0);
      }
    __builtin_amdgcn_s_setprio(0);

    if (flag != 2) {  // mixed/empty tile: per-element mask fallback
#pragma unroll
      for (int kk = 0; kk < 2; ++kk)
#pragma unroll
        for (int r = 0; r < 16; ++r) {
          const int key = kbase + kk * 32 + (r & 3) + ((r >> 2) << 3) + (hi << 2);
          if (!mask[mbase + (size_t)qrow * SEQ + key]) sc[kk][r] = -1e30f;
        }
    }

    // ---- P = exp2(S^T); pack bf16; permlane32_swap -> PA A-frags in regs ----
    bf16x8 pa[4];
#pragma unroll
    for (int kk = 0; kk < 2; ++kk) {
      float pv[16];
#pragma unroll
      for (int r = 0; r < 16; ++r) pv[r] = __builtin_amdgcn_exp2f(sc[kk][r]);
#pragma unroll
      for (int half = 0; half < 2; ++half) {
        const int bs = half * 8;
        unsigned a0 = pk_bf16(pv[bs + 0], pv[bs + 1]);
        unsigned a1 = pk_bf16(pv[bs + 2], pv[bs + 3]);
        unsigned b0 = pk_bf16(pv[bs + 4], pv[bs + 5]);
        unsigned b1 = pk_bf16(pv[bs + 6], pv[bs + 7]);
        asm("v_permlane32_swap_b32 %0, %1" : "+v"(a0), "+v"(b0));
        asm("v_permlane32_swap_b32 %0, %1" : "+v"(a1), "+v"(b1));
        union { unsigned u[4]; bf16x8 v; } uu;
        uu.u[0] = a0; uu.u[1] = a1; uu.u[2] = b0; uu.u[3] = b1;
        pa[kk * 2 + half] = uu.v;
      }
    }

    // ---- O += P·V (B-frags from Vbuf[cur], paired-row layout); l += P·ones --
    const ushort_t* Vc = &Vbuf[cur][0];
    __builtin_amdgcn_s_setprio(1);
#pragma unroll
    for (int ks = 0; ks < 4; ++ks) {
#pragma unroll
      for (int dt = 0; dt < 4; ++dt) {
        const int d = dt * 32 + q31;  // B-col = lane&31
        const int vr = d >> 1;
        const int clog = ((d & 1) << 3) + (ks << 1) + hi;
        const bf16x8 vf =
            *(const bf16x8*)&Vc[vr * 128 + (clog ^ (vr & 15)) * 8];
        oacc[dt] = __builtin_amdgcn_mfma_f32_32x32x16_bf16(pa[ks], vf,
                                                           oacc[dt], 0, 0, 0);
      }
      lacc = __builtin_amdgcn_mfma_f32_32x32x16_bf16(pa[ks], onesf, lacc,
                                                     0, 0, 0);
    }
    __builtin_amdgcn_s_setprio(0);
    cur ^= 1;
  }

  // ---- epilogue: l lives in col 0 (lanes 0 and 32); D row = q = crow ----
#pragma unroll
  for (int r = 0; r < 16; ++r) {
    const float ls = __shfl(lacc[r], l & 32, 64);
    const float invl = 1.0f / ls;
    const int row = b * SEQ + qbase + w * 32 + (r & 3) + ((r >> 2) << 3) +
                    (hi << 2);
#pragma unroll
    for (int dt = 0; dt < 4; ++dt)
      Ab[(size_t)row * HIDDEN + h * HD + dt * 32 + q31] =
          f2bf(oacc[dt][r] * invl);
  }
}

// ---------------------------------------------------------------------------
extern "C" void kernel_launch(void* const* d_in, const int* in_sizes, int n_in,
                              void* d_out, int out_size, void* d_ws, size_t ws_size,
                              hipStream_t stream) {
  const float* X  = (const float*)d_in[0];
  const int* mask = (const int*)d_in[1];
  const float* Wq = (const float*)d_in[2];
  const float* bq = (const float*)d_in[3];
  const float* Wk = (const float*)d_in[4];
  const float* bk = (const float*)d_in[5];
  const float* Wv = (const float*)d_in[6];
  const float* bv = (const float*)d_in[7];
  const float* Wo = (const float*)d_in[8];
  const float* bo = (const float*)d_in[9];
  float* out = (float*)d_out;

  char* p = (char*)d_ws;
  int* flags     = (int*)p;      p += BSZ * 16 * 32 * 4;   // 4 KB
  float* biasQKV = (float*)p;    p += 16384;  // NQKV floats = 9216 B; 16 KB reserved
  ushort_t* QKVb = (ushort_t*)p; p += (size_t)MTOT * NQKV * 2;
  ushort_t* Xb   = (ushort_t*)p; p += (size_t)MTOT * HIDDEN * 2;  // reused as Ab
  ushort_t* WT   = (ushort_t*)p; p += (size_t)NQKV * HIDDEN * 2;
  ushort_t* WoT  = (ushort_t*)p; p += (size_t)HIDDEN * HIDDEN * 2;
  ushort_t* Vt   = (ushort_t*)p; p += (size_t)HD * MTOT * 2;
  ushort_t* Ab = Xb;  // X consumed by QKV GEMM before flash writes Ab

  // fused preprocessing (mask flags, cvt, weight transposes, bias)
  prep_kernel<<<PREP_NB, 256, 0, stream>>>(
      X, Xb, Wq, Wk, Wv, WT, Wo, WoT, mask, flags, bq, bk, bv, biasQKV);

  // QKV projection: M=4096 (32 m-tiles), N=2304 (18 n-tiles); nm/8 = 4.
  // Epilogue also writes Vt via LDS-staged coalesced transpose (n-tile 17).
  gemm_mfma<0, 1><<<dim3((MTOT / 128) * (NQKV / 128)), 256, 0, stream>>>(
      Xb, WT, biasQKV, QKVb, Vt, MTOT, NQKV, HIDDEN, (MTOT / 128) / 8);
  flash_mfma<<<dim3(SEQ / 128, HEADS, BSZ), 256, 0, stream>>>(
      QKVb, Vt, mask, flags, Ab);
  // O projection: M=4096 (32 m-tiles), N=2048 (16 n-tiles)
  gemm_mfma<1, 0><<<dim3((MTOT / 128) * (HIDDEN / 128)), 256, 0, stream>>>(
      Ab, WoT, bo, out, nullptr, MTOT, HIDDEN, HIDDEN, (MTOT / 128) / 8);
}

// Round 13
// 311.378 us; speedup vs baseline: 1.1650x; 1.0080x over previous
//
#include <hip/hip_runtime.h>
#include <cstdint>
#include <cstddef>

#define HIDDEN 2048
#define HEADS 16
#define HD 128
#define BSZ 2
#define SEQ 2048
#define MTOT (BSZ * SEQ)        // 4096
#define NQKV (HIDDEN + 2 * HD)  // 2304
#define SL2E 0.12751743f        // (1/sqrt(128)) * log2(e)

typedef unsigned short ushort_t;
typedef __attribute__((ext_vector_type(8))) __bf16 bf16x8;
typedef __attribute__((ext_vector_type(4))) float f32x4;
typedef __attribute__((ext_vector_type(16))) float f32x16;

typedef __attribute__((address_space(3))) unsigned int as3_u32;
typedef __attribute__((address_space(1))) const unsigned int as1_u32;

// fp32 -> bf16 round-to-nearest-even
__device__ __forceinline__ ushort_t f2bf(float x) {
  union { float f; unsigned u; } v; v.f = x;
  unsigned r = v.u + 0x7fffu + ((v.u >> 16) & 1u);
  return (ushort_t)(r >> 16);
}
// pack two fp32 -> bf16x2 (truncation; bias cancels in normalized softmax)
__device__ __forceinline__ unsigned pk_bf16(float a, float b) {
  union { float f; unsigned u; } x, y; x.f = a; y.f = b;
  return (x.u >> 16) | (y.u & 0xFFFF0000u);
}

// async global->LDS, 16B per lane; lds dst is wave-uniform (HW adds lane*16)
__device__ __forceinline__ void gld16(const void* g, void* lds) {
  __builtin_amdgcn_global_load_lds((as1_u32*)g, (as3_u32*)lds, 16, 0, 0);
}

// ---------------------------------------------------------------------------
// Fused preprocessing (proven round 9; biasQKV 16 KB — the 4096 B alloc was
// the rounds-6-8 corruption bug). Block ranges (256-thread, block-uniform):
//   [0, NM) mask_flags | [NM,+N0) cvt_bf16 | +N1 cvtT_qkv | +N2 cvtT | +N4 bias
// ---------------------------------------------------------------------------
#define PREP_NM (32 * 16 * BSZ)                  // 1024
#define PREP_N0 (MTOT * HIDDEN / 4 / 256)        // 8192
#define PREP_N1 ((NQKV / 32) * (HIDDEN / 32))    // 4608
#define PREP_N2 ((HIDDEN / 32) * (HIDDEN / 32))  // 4096
#define PREP_N4 ((NQKV + 255) / 256)             // 9
#define PREP_NB (PREP_NM + PREP_N0 + PREP_N1 + PREP_N2 + PREP_N4)

__global__ __launch_bounds__(256) void prep_kernel(
    const float* __restrict__ X, ushort_t* __restrict__ Xb,
    const float* __restrict__ Wq, const float* __restrict__ Wk,
    const float* __restrict__ Wv, ushort_t* __restrict__ WT,
    const float* __restrict__ Wo, ushort_t* __restrict__ WoT,
    const int* __restrict__ mask, int* __restrict__ flags,
    const float* __restrict__ bq, const float* __restrict__ bk,
    const float* __restrict__ bv, float* __restrict__ biasQKV) {
  __shared__ float tileF[32][36];
  __shared__ int sAO[8];
  const int t = threadIdx.x;
  int j = blockIdx.x;

  if (j < PREP_NM) {  // ---- mask_flags (long-pole blocks first) ----
    const int kt = j & 31, qt = (j >> 5) & 15, b = j >> 9;
    int allv = 1, anyv = 0;
    const size_t base = (size_t)b * SEQ * SEQ + (size_t)qt * 128 * SEQ + kt * 64;
    for (int i = t; i < 2048; i += 256) {  // 128 rows x 16 int4
      const int row = i >> 4, c4 = (i & 15) << 2;
      const int4 v = *(const int4*)(mask + base + (size_t)row * SEQ + c4);
      const int nz = (v.x != 0) & (v.y != 0) & (v.z != 0) & (v.w != 0);
      const int nzany = (v.x != 0) | (v.y != 0) | (v.z != 0) | (v.w != 0);
      allv &= nz; anyv |= nzany;
    }
    const int wAll = __all(allv), wAny = __any(anyv);
    if ((t & 63) == 0) { sAO[t >> 6] = wAll; sAO[4 + (t >> 6)] = wAny; }
    __syncthreads();
    if (t == 0) {
      const int A = sAO[0] & sAO[1] & sAO[2] & sAO[3];
      const int O = sAO[4] | sAO[5] | sAO[6] | sAO[7];
      flags[(b * 16 + qt) * 32 + kt] = A ? 2 : (O ? 1 : 0);
    }
    return;
  }
  j -= PREP_NM;

  if (j < PREP_N0) {  // ---- cvt_bf16 (exact coverage, no bounds check) ----
    const int i = j * 256 + t;
    float4 v = ((const float4*)X)[i];
    ushort4 o;
    o.x = f2bf(v.x); o.y = f2bf(v.y); o.z = f2bf(v.z); o.w = f2bf(v.w);
    ((ushort4*)Xb)[i] = o;
    return;
  }
  j -= PREP_N0;

  if (j < PREP_N1) {  // ---- cvtT_qkv ----
    const int nb = (j % (NQKV / 32)) * 32, kb = (j / (NQKV / 32)) * 32;
    const float* W; int N, nc; float scale;
    if (nb < HIDDEN)           { W = Wq; N = HIDDEN; nc = nb;               scale = SL2E; }
    else if (nb < HIDDEN + HD) { W = Wk; N = HD;     nc = nb - HIDDEN;      scale = 1.f; }
    else                       { W = Wv; N = HD;     nc = nb - HIDDEN - HD; scale = 1.f; }
    {
      int row = t >> 3, c4 = (t & 7) << 2;
      float4 v = *(const float4*)(W + (size_t)(kb + row) * N + nc + c4);
      tileF[row][c4] = v.x * scale; tileF[row][c4 + 1] = v.y * scale;
      tileF[row][c4 + 2] = v.z * scale; tileF[row][c4 + 3] = v.w * scale;
    }
    __syncthreads();
    {
      int nl = t >> 3, k4 = (t & 7) << 2;
      ushort4 o;
      o.x = f2bf(tileF[k4 + 0][nl]); o.y = f2bf(tileF[k4 + 1][nl]);
      o.z = f2bf(tileF[k4 + 2][nl]); o.w = f2bf(tileF[k4 + 3][nl]);
      *(ushort4*)(WT + (size_t)(nb + nl) * HIDDEN + kb + k4) = o;
    }
    return;
  }
  j -= PREP_N1;

  if (j < PREP_N2) {  // ---- cvtT (Wo -> WoT), K=N=HIDDEN ----
    const int nb = (j % (HIDDEN / 32)) * 32, kb = (j / (HIDDEN / 32)) * 32;
    {
      int row = t >> 3, c4 = (t & 7) << 2;
      float4 v = *(const float4*)(Wo + (size_t)(kb + row) * HIDDEN + nb + c4);
      tileF[row][c4] = v.x; tileF[row][c4 + 1] = v.y;
      tileF[row][c4 + 2] = v.z; tileF[row][c4 + 3] = v.w;
    }
    __syncthreads();
    {
      int nl = t >> 3, k4 = (t & 7) << 2;
      ushort4 o;
      o.x = f2bf(tileF[k4 + 0][nl]); o.y = f2bf(tileF[k4 + 1][nl]);
      o.z = f2bf(tileF[k4 + 2][nl]); o.w = f2bf(tileF[k4 + 3][nl]);
      *(ushort4*)(WoT + (size_t)(nb + nl) * HIDDEN + kb + k4) = o;
    }
    return;
  }
  j -= PREP_N2;

  {  // ---- concat_bias ----
    const int i = j * 256 + t;
    if (i < NQKV)
      biasQKV[i] = (i < HIDDEN) ? bq[i] * SL2E
                 : (i < HIDDEN + HD ? bk[i - HIDDEN] : bv[i - HIDDEN - HD]);
  }
}

// ---------------------------------------------------------------------------
// bf16 MFMA GEMM, 2-phase 128x128 double-buffered (proven best; unchanged
// from the 313.9us build). FUSEV: V tile transposed through reused LDS and
// written coalesced (r12-validated).
// ---------------------------------------------------------------------------
template <int OUTF32, int FUSEV>
__global__ __launch_bounds__(256) void gemm_mfma(
    const ushort_t* __restrict__ A, const ushort_t* __restrict__ Bt,
    const float* __restrict__ bias, void* __restrict__ C,
    ushort_t* __restrict__ Vt, int M, int N, int K, int nm_per_xcd) {
  __shared__ ushort_t Smem[4 * 128 * 64];  // 64 KB: As[2] | Bs[2]
  ushort_t (*As)[128 * 64] = reinterpret_cast<ushort_t(*)[128 * 64]>(Smem);
  ushort_t (*Bs)[128 * 64] =
      reinterpret_cast<ushort_t(*)[128 * 64]>(Smem + 2 * 128 * 64);
  const int t = threadIdx.x;
  const int w = t >> 6, l = t & 63;
  const int id = blockIdx.x;
  const int xcd = id & 7, j = id >> 3;
  const int mt = xcd * nm_per_xcd + (j % nm_per_xcd);
  const int nt = j / nm_per_xcd;
  const int mb = mt * 128, nb = nt * 128;
  const int wm = (w >> 1) * 64, wn = (w & 1) * 64;
  const int fl = l & 15, g = l >> 4;
  const int srow = l >> 3, cphys = l & 7;

  f32x4 acc[4][4];
#pragma unroll
  for (int i = 0; i < 4; ++i)
#pragma unroll
    for (int jj = 0; jj < 4; ++jj) acc[i][jj] = (f32x4){0.f, 0.f, 0.f, 0.f};

#pragma unroll
  for (int jj = 0; jj < 4; ++jj) {
    const int inst = w * 4 + jj;
    const int row = inst * 8 + srow;
    const int clog = cphys ^ (row & 7);
    gld16(A + (size_t)(mb + row) * K + clog * 8, &As[0][inst * 512]);
    gld16(Bt + (size_t)(nb + row) * K + clog * 8, &Bs[0][inst * 512]);
  }

  int cur = 0;
  for (int k0 = 0; k0 < K; k0 += 64) {
    __syncthreads();
    if (k0 + 64 < K) {
#pragma unroll
      for (int jj = 0; jj < 4; ++jj) {
        const int inst = w * 4 + jj;
        const int row = inst * 8 + srow;
        const int clog = cphys ^ (row & 7);
        gld16(A + (size_t)(mb + row) * K + k0 + 64 + clog * 8,
              &As[cur ^ 1][inst * 512]);
        gld16(Bt + (size_t)(nb + row) * K + k0 + 64 + clog * 8,
              &Bs[cur ^ 1][inst * 512]);
      }
    }
    const ushort_t* Ac = &As[cur][0];
    const ushort_t* Bc = &Bs[cur][0];
#pragma unroll
    for (int s = 0; s < 2; ++s) {
      bf16x8 af[4], bfr[4];
#pragma unroll
      for (int i = 0; i < 4; ++i) {
        const int m = wm + i * 16 + fl;
        af[i] = *(const bf16x8*)&Ac[m * 64 + (((s << 2) + g) ^ (m & 7)) * 8];
        const int n = wn + i * 16 + fl;
        bfr[i] = *(const bf16x8*)&Bc[n * 64 + (((s << 2) + g) ^ (n & 7)) * 8];
      }
#pragma unroll
      for (int i = 0; i < 4; ++i)
#pragma unroll
        for (int jj = 0; jj < 4; ++jj)
          acc[i][jj] = __builtin_amdgcn_mfma_f32_16x16x32_bf16(
              af[i], bfr[jj], acc[i][jj], 0, 0, 0);
    }
    cur ^= 1;
  }

  // V-transpose staging only for the QKV GEMM's V n-tile (nb==2176);
  // branch is block-uniform.
  const bool dofv = FUSEV && (nb == HIDDEN + HD);
  if (dofv) __syncthreads();  // all waves done reading As/Bs; Smem reusable

  // epilogue: C stores (+ LDS-staged V tile for dofv blocks)
#pragma unroll
  for (int jj = 0; jj < 4; ++jj) {
    const int col = nb + wn + jj * 16 + fl;
    const float bv = bias[col];
#pragma unroll
    for (int i = 0; i < 4; ++i) {
      const int row0 = mb + wm + i * 16 + g * 4;
#pragma unroll
      for (int r = 0; r < 4; ++r) {
        const float val = acc[i][jj][r] + bv;
        if (OUTF32) {
          ((float*)C)[(size_t)(row0 + r) * N + col] = val;
        } else {
          const ushort_t bb = f2bf(val);
          ((ushort_t*)C)[(size_t)(row0 + r) * N + col] = bb;
          if (dofv) {
            const int cl = wn + jj * 16 + fl;
            const int rl = row0 - mb + r;
            Smem[cl * 132 + rl] = bb;
          }
        }
      }
    }
  }

  if (dofv) {
    __syncthreads();
    // coalesced write-out: 128 d-rows x 128 cols; each thread 16x ushort4
    const int c4 = (t & 31) * 4;
#pragma unroll
    for (int k = 0; k < 16; ++k) {
      const int d = k * 8 + (t >> 5);
      const ushort4 v = *(const ushort4*)&Smem[d * 132 + c4];
      *(ushort4*)(Vt + (size_t)d * MTOT + mb + c4) = v;
    }
  }
}

// ---------------------------------------------------------------------------
// MFMA flash attention, round-19: single-buffered V -> LDS 64->48 KB ->
// 3 blocks/CU (was 2). Rationale: at 2 waves/SIMD the three pipes (LDS-read
// ~41us, VALU ~26us, MFMA ~32us) barely overlap -> 83us = 2x max-pipe floor.
// V(t) is consumed LATE in tile t (after QK+softmax ~500cyc), so it can be
// staged inside tile t after the top barrier (PV(t-1) retired). Per wave:
// issue 4 V(t) loads THEN 4 K(t+1) loads; before PV: vmcnt(4) (own V done,
// K prefetch stays in flight - never drain to 0) + s_barrier (all waves
// passed their vmcnt(4) -> whole V tile landed) + sched_barrier(0) (keep
// hipcc from hoisting PV ds_reads past the asm wait). Top-of-tile
// __syncthreads (full drain) retires K(t+1) exactly as before.
// VGPR 124 fits 3 blocks/CU (16-wave VGPR cap); launch_bounds unchanged.
// ---------------------------------------------------------------------------
__global__ __launch_bounds__(256, 2) void flash_mfma(
    const ushort_t* __restrict__ QKV,  // (4096, 2304) bf16; Q pre-scaled
    const ushort_t* __restrict__ Vt,   // (128, 4096) bf16
    const int* __restrict__ mask,      // (B, S, S)
    const int* __restrict__ flags,     // (B, 16, 32)
    ushort_t* __restrict__ Ab)         // (4096, 2048) bf16
{
  __shared__ ushort_t Kbuf[2][64 * 128];  // 32 KB: key rows x 128 k-dim
  __shared__ ushort_t Vbuf[64 * 128];     // 16 KB: single-buffered

  const int qt = blockIdx.x, h = blockIdx.y, b = blockIdx.z;
  const int t = threadIdx.x, w = t >> 6, l = t & 63;
  const int q31 = l & 31, hi = l >> 5;
  const int qbase = qt * 128;
  const int qrow = qbase + w * 32 + q31;  // within-batch q row (B-col index)

  // Q as B-fragments: col=q31, k = ks*16 + hi*8 + j (exp2 domain, pre-scaled)
  bf16x8 qf[8];
#pragma unroll
  for (int ks = 0; ks < 8; ++ks)
    qf[ks] = *(const bf16x8*)(QKV + (size_t)(b * SEQ + qrow) * NQKV + h * HD +
                              ks * 16 + hi * 8);

  // ones B-frag for l: B[col=q31][k] = (q31==0) ? 1.0 : 0
  bf16x8 onesf;
  {
    const ushort_t ov = (q31 == 0) ? (ushort_t)0x3F80 : (ushort_t)0;
#pragma unroll
    for (int jj = 0; jj < 8; ++jj) ((ushort_t*)&onesf)[jj] = ov;
  }

  // prologue: prefetch K(0) -> Kbuf[0] (V staged in-tile; single buffer)
#pragma unroll
  for (int j = 0; j < 4; ++j) {
    const int inst = w * 4 + j;
    const int krow = inst * 4 + (l >> 4);
    const int ck = (l & 15) ^ (krow & 15);
    gld16(QKV + (size_t)(b * SEQ + krow) * NQKV + HIDDEN + ck * 8,
          &Kbuf[0][inst * 512]);
  }

  const size_t mbase = (size_t)b * SEQ * SEQ;

  f32x16 oacc[4], lacc;
#pragma unroll
  for (int d = 0; d < 4; ++d)
#pragma unroll
    for (int r = 0; r < 16; ++r) oacc[d][r] = 0.f;
#pragma unroll
  for (int r = 0; r < 16; ++r) lacc[r] = 0.f;

  int cur = 0;
  for (int kt = 0; kt < SEQ / 64; ++kt) {
    const int kbase = kt * 64;
    const int flag = flags[((b * 16 + qt) << 5) + kt];  // block-uniform
    __syncthreads();  // full drain: K(kt) landed; all waves' PV(kt-1) retired

    // stage V(kt) -> Vbuf (4 loads FIRST; single buffer, freed by barrier)
#pragma unroll
    for (int j = 0; j < 4; ++j) {
      const int inst = w * 4 + j;
      const int vr = inst * 4 + (l >> 4);
      const int clog = (l & 15) ^ (vr & 15);
      const int d = 2 * vr + (clog >> 3);
      gld16(Vt + (size_t)d * MTOT + b * SEQ + kbase + (clog & 7) * 8,
            &Vbuf[inst * 512]);
    }
    // prefetch K(kt+1) -> Kbuf[cur^1] (clamped on last tile; stays in flight
    // across the mid-tile vmcnt(4), retires at next tile's __syncthreads)
    {
      const int knb = (kt + 1 < SEQ / 64) ? (kbase + 64) : kbase;
#pragma unroll
      for (int j = 0; j < 4; ++j) {
        const int inst = w * 4 + j;
        const int krow = inst * 4 + (l >> 4);
        const int ck = (l & 15) ^ (krow & 15);
        gld16(QKV + (size_t)(b * SEQ + knb + krow) * NQKV + HIDDEN + ck * 8,
              &Kbuf[cur ^ 1][inst * 512]);
      }
    }

    // ---- S^T = K·Q^T from Kbuf[cur]: A = K rows (key), B = Q cols (q) ----
    const ushort_t* Kc = &Kbuf[cur][0];
    f32x16 sc[2];
#pragma unroll
    for (int kk = 0; kk < 2; ++kk)
#pragma unroll
      for (int r = 0; r < 16; ++r) sc[kk][r] = 0.f;

    __builtin_amdgcn_s_setprio(1);
#pragma unroll
    for (int ks = 0; ks < 8; ++ks)
#pragma unroll
      for (int kk = 0; kk < 2; ++kk) {
        const int key = kk * 32 + q31;  // A-row = lane&31
        const bf16x8 kf = *(const bf16x8*)&Kc[key * 128 +
                                              (((ks << 1) + hi) ^ (key & 15)) * 8];
        sc[kk] = __builtin_amdgcn_mfma_f32_32x32x16_bf16(kf, qf[ks], sc[kk],
                                                         0, 0, 0);
      }
    __builtin_amdgcn_s_setprio(0);

    if (flag != 2) {  // mixed/empty tile: per-element mask fallback
#pragma unroll
      for (int kk = 0; kk < 2; ++kk)
#pragma unroll
        for (int r = 0; r < 16; ++r) {
          const int key = kbase + kk * 32 + (r & 3) + ((r >> 2) << 3) + (hi << 2);
          if (!mask[mbase + (size_t)qrow * SEQ + key]) sc[kk][r] = -1e30f;
        }
    }

    // ---- P = exp2(S^T); pack bf16; permlane32_swap -> PA A-frags in regs ----
    bf16x8 pa[4];
#pragma unroll
    for (int kk = 0; kk < 2; ++kk) {
      float pv[16];
#pragma unroll
      for (int r = 0; r < 16; ++r) pv[r] = __builtin_amdgcn_exp2f(sc[kk][r]);
#pragma unroll
      for (int half = 0; half < 2; ++half) {
        const int bs = half * 8;
        unsigned a0 = pk_bf16(pv[bs + 0], pv[bs + 1]);
        unsigned a1 = pk_bf16(pv[bs + 2], pv[bs + 3]);
        unsigned b0 = pk_bf16(pv[bs + 4], pv[bs + 5]);
        unsigned b1 = pk_bf16(pv[bs + 6], pv[bs + 7]);
        asm("v_permlane32_swap_b32 %0, %1" : "+v"(a0), "+v"(b0));
        asm("v_permlane32_swap_b32 %0, %1" : "+v"(a1), "+v"(b1));
        union { unsigned u[4]; bf16x8 v; } uu;
        uu.u[0] = a0; uu.u[1] = a1; uu.u[2] = b0; uu.u[3] = b1;
        pa[kk * 2 + half] = uu.v;
      }
    }

    // ---- V(kt) ready-wait: own V loads retired (vmcnt(4): K prefetch may
    // stay in flight), then barrier -> ALL waves' V loads landed ----
    asm volatile("s_waitcnt vmcnt(4)" ::: "memory");
    __builtin_amdgcn_s_barrier();
    asm volatile("" ::: "memory");
    __builtin_amdgcn_sched_barrier(0);

    // ---- O += P·V (B-frags from Vbuf, paired-row layout); l += P·ones ----
    __builtin_amdgcn_s_setprio(1);
#pragma unroll
    for (int ks = 0; ks < 4; ++ks) {
#pragma unroll
      for (int dt = 0; dt < 4; ++dt) {
        const int d = dt * 32 + q31;  // B-col = lane&31
        const int vr = d >> 1;
        const int clog = ((d & 1) << 3) + (ks << 1) + hi;
        const bf16x8 vf =
            *(const bf16x8*)&Vbuf[vr * 128 + (clog ^ (vr & 15)) * 8];
        oacc[dt] = __builtin_amdgcn_mfma_f32_32x32x16_bf16(pa[ks], vf,
                                                           oacc[dt], 0, 0, 0);
      }
      lacc = __builtin_amdgcn_mfma_f32_32x32x16_bf16(pa[ks], onesf, lacc,
                                                     0, 0, 0);
    }
    __builtin_amdgcn_s_setprio(0);
    cur ^= 1;
  }

  // ---- epilogue: l lives in col 0 (lanes 0 and 32); D row = q = crow ----
#pragma unroll
  for (int r = 0; r < 16; ++r) {
    const float ls = __shfl(lacc[r], l & 32, 64);
    const float invl = 1.0f / ls;
    const int row = b * SEQ + qbase + w * 32 + (r & 3) + ((r >> 2) << 3) +
                    (hi << 2);
#pragma unroll
    for (int dt = 0; dt < 4; ++dt)
      Ab[(size_t)row * HIDDEN + h * HD + dt * 32 + q31] =
          f2bf(oacc[dt][r] * invl);
  }
}

// ---------------------------------------------------------------------------
extern "C" void kernel_launch(void* const* d_in, const int* in_sizes, int n_in,
                              void* d_out, int out_size, void* d_ws, size_t ws_size,
                              hipStream_t stream) {
  const float* X  = (const float*)d_in[0];
  const int* mask = (const int*)d_in[1];
  const float* Wq = (const float*)d_in[2];
  const float* bq = (const float*)d_in[3];
  const float* Wk = (const float*)d_in[4];
  const float* bk = (const float*)d_in[5];
  const float* Wv = (const float*)d_in[6];
  const float* bv = (const float*)d_in[7];
  const float* Wo = (const float*)d_in[8];
  const float* bo = (const float*)d_in[9];
  float* out = (float*)d_out;

  char* p = (char*)d_ws;
  int* flags     = (int*)p;      p += BSZ * 16 * 32 * 4;   // 4 KB
  float* biasQKV = (float*)p;    p += 16384;  // NQKV floats = 9216 B; 16 KB reserved
  ushort_t* QKVb = (ushort_t*)p; p += (size_t)MTOT * NQKV * 2;
  ushort_t* Xb   = (ushort_t*)p; p += (size_t)MTOT * HIDDEN * 2;  // reused as Ab
  ushort_t* WT   = (ushort_t*)p; p += (size_t)NQKV * HIDDEN * 2;
  ushort_t* WoT  = (ushort_t*)p; p += (size_t)HIDDEN * HIDDEN * 2;
  ushort_t* Vt   = (ushort_t*)p; p += (size_t)HD * MTOT * 2;
  ushort_t* Ab = Xb;  // X consumed by QKV GEMM before flash writes Ab

  // fused preprocessing (mask flags, cvt, weight transposes, bias)
  prep_kernel<<<PREP_NB, 256, 0, stream>>>(
      X, Xb, Wq, Wk, Wv, WT, Wo, WoT, mask, flags, bq, bk, bv, biasQKV);

  // QKV projection: M=4096 (32 m-tiles), N=2304 (18 n-tiles); nm/8 = 4.
  // Epilogue also writes Vt via LDS-staged coalesced transpose (n-tile 17).
  gemm_mfma<0, 1><<<dim3((MTOT / 128) * (NQKV / 128)), 256, 0, stream>>>(
      Xb, WT, biasQKV, QKVb, Vt, MTOT, NQKV, HIDDEN, (MTOT / 128) / 8);
  flash_mfma<<<dim3(SEQ / 128, HEADS, BSZ), 256, 0, stream>>>(
      QKVb, Vt, mask, flags, Ab);
  // O projection: M=4096 (32 m-tiles), N=2048 (16 n-tiles)
  gemm_mfma<1, 0><<<dim3((MTOT / 128) * (HIDDEN / 128)), 256, 0, stream>>>(
      Ab, WoT, bo, out, nullptr, MTOT, HIDDEN, HIDDEN, (MTOT / 128) / 8);
}